// Round 1
// baseline (1367.955 us; speedup 1.0000x reference)
//
#include <hip/hip_runtime.h>

#define NU 50000
#define NI 100000
#define NT 150000
#define BB 4096

__device__ __forceinline__ float softplusf(float x) {
  return fmaxf(x, 0.f) + log1pf(expf(-fabsf(x)));
}
__device__ __forceinline__ float wsum(float v) {
#pragma unroll
  for (int o = 32; o > 0; o >>= 1) v += __shfl_xor(v, o, 64);
  return v;
}
__device__ __forceinline__ float wmax(float v) {
#pragma unroll
  for (int o = 32; o > 0; o >>= 1) v = fmaxf(v, __shfl_xor(v, o, 64));
  return v;
}

__global__ void k_hist(const int* __restrict__ h, int* __restrict__ hist, int E) {
  int e = blockIdx.x * 256 + threadIdx.x;
  if (e < E) atomicAdd(&hist[h[e]], 1);
}

__global__ void k_scanA(const int* __restrict__ hist, int* __restrict__ partial, int n) {
  __shared__ int sd[256];
  int base = blockIdx.x * 1024;
  int s = 0;
  for (int j = threadIdx.x; j < 1024; j += 256) {
    int idx = base + j;
    if (idx < n) s += hist[idx];
  }
  sd[threadIdx.x] = s;
  __syncthreads();
  for (int o = 128; o > 0; o >>= 1) {
    if (threadIdx.x < o) sd[threadIdx.x] += sd[threadIdx.x + o];
    __syncthreads();
  }
  if (threadIdx.x == 0) partial[blockIdx.x] = sd[0];
}

__global__ void k_scanB(int* __restrict__ partial, int nblk, int* __restrict__ row_ptr, int n) {
  if (threadIdx.x == 0 && blockIdx.x == 0) {
    int run = 0;
    for (int i = 0; i < nblk; i++) { int t = partial[i]; partial[i] = run; run += t; }
    row_ptr[n] = run;
  }
}

__global__ void k_scanC(const int* __restrict__ hist, const int* __restrict__ partial,
                        int* __restrict__ row_ptr, float* __restrict__ d_inv, int n) {
  __shared__ int sd[256];
  int t = threadIdx.x;
  int base = blockIdx.x * 1024 + t * 4;
  int v0 = 0, v1 = 0, v2 = 0, v3 = 0;
  if (base + 0 < n) v0 = hist[base + 0];
  if (base + 1 < n) v1 = hist[base + 1];
  if (base + 2 < n) v2 = hist[base + 2];
  if (base + 3 < n) v3 = hist[base + 3];
  int ts = v0 + v1 + v2 + v3;
  sd[t] = ts;
  __syncthreads();
  for (int o = 1; o < 256; o <<= 1) {
    int x = (t >= o) ? sd[t - o] : 0;
    __syncthreads();
    sd[t] += x;
    __syncthreads();
  }
  int run = partial[blockIdx.x] + sd[t] - ts;
  if (base + 0 < n) { row_ptr[base + 0] = run; run += v0; d_inv[base + 0] = 1.0f / sqrtf((float)v0); }
  if (base + 1 < n) { row_ptr[base + 1] = run; run += v1; d_inv[base + 1] = 1.0f / sqrtf((float)v1); }
  if (base + 2 < n) { row_ptr[base + 2] = run; run += v2; d_inv[base + 2] = 1.0f / sqrtf((float)v2); }
  if (base + 3 < n) { row_ptr[base + 3] = run; run += v3; d_inv[base + 3] = 1.0f / sqrtf((float)v3); }
}

__global__ void k_scatter(const int* __restrict__ h, const int* __restrict__ t,
                          const int* __restrict__ row_ptr, int* __restrict__ cursor,
                          const float* __restrict__ d_inv, uint2* __restrict__ edges, int E) {
  int e = blockIdx.x * 256 + threadIdx.x;
  if (e >= E) return;
  int hh = h[e], tt = t[e];
  int pos = row_ptr[hh] + atomicAdd(&cursor[hh], 1);
  float g = d_inv[hh] * d_inv[tt];
  uint2 v; v.x = (unsigned)tt; v.y = __float_as_uint(g);
  edges[pos] = v;
}

__global__ void k_init(const float4* __restrict__ ue, const float4* __restrict__ ie,
                       float4* __restrict__ cur, float4* __restrict__ acc, int nU4, int nTot4) {
  int i = blockIdx.x * 256 + threadIdx.x;
  if (i >= nTot4) return;
  float4 v = (i < nU4) ? ue[i] : ie[i - nU4];
  cur[i] = v;
  acc[i] = v;
}

__global__ __launch_bounds__(256) void k_agg(const int* __restrict__ row_ptr,
                                             const uint2* __restrict__ edges,
                                             const float* __restrict__ cur,
                                             float* __restrict__ nxt,
                                             float* __restrict__ acc) {
  int node = (blockIdx.x << 2) + (threadIdx.x >> 6);
  int lane = threadIdx.x & 63;
  if (node >= NT) return;
  int s = row_ptr[node], e = row_ptr[node + 1];
  float sum = 0.f;
  int i = s;
  for (; i + 1 < e; i += 2) {
    uint2 a = edges[i], b = edges[i + 1];
    float ca = cur[a.x * 64 + lane];
    float cb = cur[b.x * 64 + lane];
    sum = fmaf(__uint_as_float(a.y), ca, sum);
    sum = fmaf(__uint_as_float(b.y), cb, sum);
  }
  if (i < e) {
    uint2 a = edges[i];
    sum = fmaf(__uint_as_float(a.y), cur[a.x * 64 + lane], sum);
  }
  int o = node * 64 + lane;
  nxt[o] = sum;
  acc[o] += sum;
}

__global__ __launch_bounds__(256) void k_kl(const float* __restrict__ acc,
                                            const float* __restrict__ lin_w,
                                            const float* __restrict__ lin_b,
                                            double* __restrict__ accums) {
  __shared__ float lw[64 * 33];
  __shared__ float lb[64];
  for (int i = threadIdx.x; i < 64 * 32; i += 256) lw[(i >> 5) * 33 + (i & 31)] = lin_w[i];
  if (threadIdx.x < 64) lb[threadIdx.x] = lin_b[threadIdx.x];
  __syncthreads();
  int lane = threadIdx.x & 63;
  int w = (blockIdx.x * 256 + threadIdx.x) >> 6;
  int nw = (gridDim.x * 256) >> 6;
  double dsum = 0.0;
  for (int row = w; row < NT; row += nw) {
    float m = acc[row * 64 + lane];
    float sp = softplusf(m);
    float sd = lb[lane] + 1e-8f;
#pragma unroll
    for (int j = 0; j < 32; j++) sd = fmaf(__shfl(sp, j, 64), lw[lane * 33 + j], sd);
    float e2 = expf(2.f * sd);
    float kl = -0.5f * (1.f + 2.f * sd - m * m - e2);
    if (!isfinite(kl)) kl = 0.f;
    float rs = wsum(kl);
    if (lane == 0) dsum += (double)rs;
  }
  if (lane == 0) atomicAdd(&accums[1], dsum);
}

__global__ __launch_bounds__(256) void k_batch_user(
    const float* __restrict__ acc, const float* __restrict__ user_emb,
    const float* __restrict__ eps, const float* __restrict__ intent,
    const float* __restrict__ lin_w, const float* __restrict__ lin_b,
    const int* __restrict__ users, const int* __restrict__ pos_items,
    const int* __restrict__ neg_items,
    float* __restrict__ gen_o, float* __restrict__ int_o, double* __restrict__ accums) {
  __shared__ float ui[64 * 130];
  __shared__ float lw[64 * 33];
  __shared__ float lb[64];
  __shared__ double red[8];
  for (int i = threadIdx.x; i < 64 * 128; i += 256) ui[(i >> 7) * 130 + (i & 127)] = intent[i];
  for (int i = threadIdx.x; i < 64 * 32; i += 256) lw[(i >> 5) * 33 + (i & 31)] = lin_w[i];
  if (threadIdx.x < 64) lb[threadIdx.x] = lin_b[threadIdx.x];
  __syncthreads();
  int lane = threadIdx.x & 63;
  int wid = threadIdx.x >> 6;
  int b = (blockIdx.x << 2) + wid;
  int u = users[b];
  float m = acc[u * 64 + lane];
  // logits over 128 intents (2 per lane)
  int k0 = lane * 2;
  float l0 = 0.f, l1 = 0.f;
  for (int d = 0; d < 64; d++) {
    float md = __shfl(m, d, 64);
    l0 = fmaf(md, ui[d * 130 + k0], l0);
    l1 = fmaf(md, ui[d * 130 + k0 + 1], l1);
  }
  float mx = wmax(fmaxf(l0, l1));
  float p0 = expf(l0 - mx), p1 = expf(l1 - mx);
  float tot = wsum(p0 + p1);
  p0 /= tot; p1 /= tot;
  float s = 0.f;
  for (int k = 0; k < 128; k++) {
    float pk = __shfl((k & 1) ? p1 : p0, k >> 1, 64);
    s = fmaf(pk, ui[lane * 130 + k], s);
  }
  float nrm = sqrtf(wsum(s * s));
  int_o[b * 64 + lane] = s / nrm;
  // gen_emb row + normalize
  float sp = softplusf(m);
  float sd = lb[lane] + 1e-8f;
#pragma unroll
  for (int j = 0; j < 32; j++) sd = fmaf(__shfl(sp, j, 64), lw[lane * 33 + j], sd);
  float ge = m + eps[u * 64 + lane] * sd;
  float gn = sqrtf(wsum(ge * ge));
  gen_o[b * 64 + lane] = ge / gn;
  // bpr
  int pi = pos_items[b], ni = neg_items[b];
  float pv = acc[(NU + pi) * 64 + lane];
  float nv = acc[(NU + ni) * 64 + lane];
  float ps = wsum(m * pv);
  float ns = wsum(m * nv);
  float bpr = softplusf(ns - ps);
  // emb (user part)
  float ue = user_emb[u * 64 + lane];
  float es = wsum(ue * ue);
  if (lane == 0) { red[wid] = (double)bpr; red[4 + wid] = (double)es; }
  __syncthreads();
  if (threadIdx.x == 0) {
    atomicAdd(&accums[0], red[0] + red[1] + red[2] + red[3]);
    atomicAdd(&accums[2], red[4] + red[5] + red[6] + red[7]);
  }
}

__global__ __launch_bounds__(256) void k_batch_item(
    const float* __restrict__ acc, const float* __restrict__ item_emb,
    const float* __restrict__ eps, const float* __restrict__ intent,
    const float* __restrict__ lin_w, const float* __restrict__ lin_b,
    const int* __restrict__ pos_items, const int* __restrict__ neg_items,
    float* __restrict__ gen_o, float* __restrict__ int_o, double* __restrict__ accums) {
  __shared__ float ui[64 * 130];
  __shared__ float lw[64 * 33];
  __shared__ float lb[64];
  __shared__ double red[4];
  for (int i = threadIdx.x; i < 64 * 128; i += 256) ui[(i >> 7) * 130 + (i & 127)] = intent[i];
  for (int i = threadIdx.x; i < 64 * 32; i += 256) lw[(i >> 5) * 33 + (i & 31)] = lin_w[i];
  if (threadIdx.x < 64) lb[threadIdx.x] = lin_b[threadIdx.x];
  __syncthreads();
  int lane = threadIdx.x & 63;
  int wid = threadIdx.x >> 6;
  int b = (blockIdx.x << 2) + wid;
  int pi = pos_items[b], ni = neg_items[b];
  int row = NU + pi;
  float m = acc[row * 64 + lane];
  int k0 = lane * 2;
  float l0 = 0.f, l1 = 0.f;
  for (int d = 0; d < 64; d++) {
    float md = __shfl(m, d, 64);
    l0 = fmaf(md, ui[d * 130 + k0], l0);
    l1 = fmaf(md, ui[d * 130 + k0 + 1], l1);
  }
  float mx = wmax(fmaxf(l0, l1));
  float p0 = expf(l0 - mx), p1 = expf(l1 - mx);
  float tot = wsum(p0 + p1);
  p0 /= tot; p1 /= tot;
  float s = 0.f;
  for (int k = 0; k < 128; k++) {
    float pk = __shfl((k & 1) ? p1 : p0, k >> 1, 64);
    s = fmaf(pk, ui[lane * 130 + k], s);
  }
  float nrm = sqrtf(wsum(s * s));
  int_o[b * 64 + lane] = s / nrm;
  float sp = softplusf(m);
  float sd = lb[lane] + 1e-8f;
#pragma unroll
  for (int j = 0; j < 32; j++) sd = fmaf(__shfl(sp, j, 64), lw[lane * 33 + j], sd);
  float ge = m + eps[row * 64 + lane] * sd;
  float gn = sqrtf(wsum(ge * ge));
  gen_o[b * 64 + lane] = ge / gn;
  float a0 = item_emb[pi * 64 + lane];
  float a1 = item_emb[ni * 64 + lane];
  float es = wsum(a0 * a0 + a1 * a1);
  if (lane == 0) red[wid] = (double)es;
  __syncthreads();
  if (threadIdx.x == 0) atomicAdd(&accums[2], red[0] + red[1] + red[2] + red[3]);
}

__global__ void k_int(const float* __restrict__ ui, const float* __restrict__ ii,
                      double* __restrict__ accums) {
  float s = 0.f;
  for (int i = threadIdx.x; i < 64 * 128; i += 256) {
    float a = ui[i], b = ii[i];
    s = fmaf(a, a, s);
    s = fmaf(b, b, s);
  }
  s = wsum(s);
  __shared__ float red[4];
  if ((threadIdx.x & 63) == 0) red[threadIdx.x >> 6] = s;
  __syncthreads();
  if (threadIdx.x == 0) atomicAdd(&accums[3], (double)(red[0] + red[1] + red[2] + red[3]));
}

// neg_i = sum_j exp(dot(e1_i, e2_j)/TEMP); grid (64 i-tiles, 16 = pair*8 + q)
__global__ __launch_bounds__(64) void k_nce_neg(
    const float* __restrict__ ugen, const float* __restrict__ uio,
    const float* __restrict__ igen, const float* __restrict__ iio,
    float* __restrict__ negu, float* __restrict__ negi) {
  __shared__ __align__(16) float tile[4096];
  int pair = blockIdx.y >> 3, q = blockIdx.y & 7;
  const float* e1 = pair ? igen : ugen;
  const float* e2 = pair ? iio : uio;
  float* nego = pair ? negi : negu;
  int lane = threadIdx.x;
  int i = blockIdx.x * 64 + lane;
  const float4* e14 = (const float4*)(e1 + (size_t)i * 64);
  float4 r[16];
#pragma unroll
  for (int w = 0; w < 16; w++) r[w] = e14[w];
  const float4* t4 = (const float4*)tile;
  const float4* e24 = (const float4*)e2;
  float nsum = 0.f;
  for (int jt = 0; jt < 8; jt++) {
    int j0 = q * 512 + jt * 64;
    __syncthreads();
    for (int w = lane; w < 1024; w += 64) ((float4*)tile)[w] = e24[j0 * 16 + w];
    __syncthreads();
    for (int jj = 0; jj < 64; jj++) {
      float dot = 0.f;
#pragma unroll
      for (int w = 0; w < 16; w++) {
        float4 t = t4[jj * 16 + w];
        dot = fmaf(r[w].x, t.x, dot);
        dot = fmaf(r[w].y, t.y, dot);
        dot = fmaf(r[w].z, t.z, dot);
        dot = fmaf(r[w].w, t.w, dot);
      }
      nsum += expf(dot * 5.0f);
    }
  }
  atomicAdd(&nego[i], nsum);
}

__global__ __launch_bounds__(256) void k_nce_final(
    const float* __restrict__ ugen, const float* __restrict__ uio,
    const float* __restrict__ igen, const float* __restrict__ iio,
    const float* __restrict__ negu, const float* __restrict__ negi,
    double* __restrict__ accums) {
  __shared__ double red[4];
  int lane = threadIdx.x & 63, wid = threadIdx.x >> 6;
  int w = blockIdx.x * 4 + wid;  // 0..8191
  int pair = w >> 12, i = w & 4095;
  const float* e1 = pair ? igen : ugen;
  const float* e2 = pair ? iio : uio;
  const float* ng = pair ? negi : negu;
  float dot = wsum(e1[i * 64 + lane] * e2[i * 64 + lane]);
  if (lane == 0) {
    float pos = expf(dot * 5.f);
    red[wid] = (double)(-logf(pos / (ng[i] + 1e-8f) + 1e-8f));
  }
  __syncthreads();
  if (threadIdx.x == 0) atomicAdd(&accums[4], red[0] + red[1] + red[2] + red[3]);
}

__global__ void k_fin(const double* __restrict__ accums, float* __restrict__ out) {
  if (threadIdx.x == 0 && blockIdx.x == 0) {
    double bpr = accums[0] / (double)BB;
    double kl = 0.01 * accums[1] / (double)NT;
    out[0] = (float)(bpr + kl);
    out[1] = (float)(0.1 * accums[4] / (double)BB);
    out[2] = (float)(1e-5 * accums[2]);
    out[3] = (float)(1e-5 * accums[3]);
  }
}

extern "C" void kernel_launch(void* const* d_in, const int* in_sizes, int n_in,
                              void* d_out, int out_size, void* d_ws, size_t ws_size,
                              hipStream_t stream) {
  const float* user_emb = (const float*)d_in[0];
  const float* item_emb = (const float*)d_in[1];
  const float* user_int = (const float*)d_in[2];
  const float* item_int = (const float*)d_in[3];
  const float* lin_w = (const float*)d_in[4];
  const float* lin_b = (const float*)d_in[5];
  const float* eps = (const float*)d_in[6];
  const int* h_list = (const int*)d_in[7];
  const int* t_list = (const int*)d_in[8];
  const int* users = (const int*)d_in[9];
  const int* pos_items = (const int*)d_in[10];
  const int* neg_items = (const int*)d_in[11];
  float* out = (float*)d_out;
  const int E = in_sizes[7];

  char* ws = (char*)d_ws;
  size_t off = 0;
  auto take = [&](size_t bytes) -> char* {
    char* p = ws + off;
    off = (off + bytes + 255) & ~(size_t)255;
    return p;
  };
  int* hist = (int*)take((size_t)NT * 4);
  int* row_ptr = (int*)take((size_t)(NT + 1) * 4);
  int* cursor = (int*)take((size_t)NT * 4);
  float* d_inv = (float*)take((size_t)NT * 4);
  int* partial = (int*)take(1024);
  uint2* edges = (uint2*)take((size_t)E * 8);
  float* bufA = (float*)take((size_t)NT * 64 * 4);
  float* bufB = (float*)take((size_t)NT * 64 * 4);
  float* acc = (float*)take((size_t)NT * 64 * 4);
  float* ugen = (float*)take((size_t)BB * 64 * 4);
  float* igen = (float*)take((size_t)BB * 64 * 4);
  float* uio = (float*)take((size_t)BB * 64 * 4);
  float* iio = (float*)take((size_t)BB * 64 * 4);
  float* negu = (float*)take((size_t)BB * 4);
  float* negi = (float*)take((size_t)BB * 4);
  double* accums = (double*)take(64);
  if (off > ws_size) return;  // workspace too small — fail visibly

  hipMemsetAsync(hist, 0, (size_t)NT * 4, stream);
  hipMemsetAsync(cursor, 0, (size_t)NT * 4, stream);
  hipMemsetAsync(negu, 0, (size_t)BB * 4, stream);
  hipMemsetAsync(negi, 0, (size_t)BB * 4, stream);
  hipMemsetAsync(accums, 0, 64, stream);

  int gridE = (E + 255) / 256;
  int nblk = (NT + 1023) / 1024;  // 147
  k_hist<<<gridE, 256, 0, stream>>>(h_list, hist, E);
  k_scanA<<<nblk, 256, 0, stream>>>(hist, partial, NT);
  k_scanB<<<1, 64, 0, stream>>>(partial, nblk, row_ptr, NT);
  k_scanC<<<nblk, 256, 0, stream>>>(hist, partial, row_ptr, d_inv, NT);
  k_scatter<<<gridE, 256, 0, stream>>>(h_list, t_list, row_ptr, cursor, d_inv, edges, E);

  int nU4 = NU * 16, nTot4 = NT * 16;
  k_init<<<(nTot4 + 255) / 256, 256, 0, stream>>>((const float4*)user_emb, (const float4*)item_emb,
                                                  (float4*)bufA, (float4*)acc, nU4, nTot4);
  int gridAgg = (NT + 3) / 4;
  k_agg<<<gridAgg, 256, 0, stream>>>(row_ptr, edges, bufA, bufB, acc);
  k_agg<<<gridAgg, 256, 0, stream>>>(row_ptr, edges, bufB, bufA, acc);
  k_agg<<<gridAgg, 256, 0, stream>>>(row_ptr, edges, bufA, bufB, acc);

  k_kl<<<512, 256, 0, stream>>>(acc, lin_w, lin_b, accums);
  k_batch_user<<<BB / 4, 256, 0, stream>>>(acc, user_emb, eps, user_int, lin_w, lin_b,
                                           users, pos_items, neg_items, ugen, uio, accums);
  k_batch_item<<<BB / 4, 256, 0, stream>>>(acc, item_emb, eps, item_int, lin_w, lin_b,
                                           pos_items, neg_items, igen, iio, accums);
  k_int<<<1, 256, 0, stream>>>(user_int, item_int, accums);
  k_nce_neg<<<dim3(64, 16), 64, 0, stream>>>(ugen, uio, igen, iio, negu, negi);
  k_nce_final<<<(2 * BB) / 4, 256, 0, stream>>>(ugen, uio, igen, iio, negu, negi, accums);
  k_fin<<<1, 64, 0, stream>>>(accums, out);
}

// Round 2
// 1131.345 us; speedup vs baseline: 1.2091x; 1.2091x over previous
//
#include <hip/hip_runtime.h>

#define NU 50000
#define NI 100000
#define NT 150000
#define BB 4096

__device__ __forceinline__ float softplusf(float x) {
  return fmaxf(x, 0.f) + log1pf(expf(-fabsf(x)));
}
__device__ __forceinline__ float wsum(float v) {
#pragma unroll
  for (int o = 32; o > 0; o >>= 1) v += __shfl_xor(v, o, 64);
  return v;
}
__device__ __forceinline__ float wmax(float v) {
#pragma unroll
  for (int o = 32; o > 0; o >>= 1) v = fmaxf(v, __shfl_xor(v, o, 64));
  return v;
}

// hist + per-edge rank in one pass
__global__ void k_hist(const int* __restrict__ h, int* __restrict__ hist,
                       int* __restrict__ rank, int E) {
  int e = blockIdx.x * 256 + threadIdx.x;
  if (e < E) rank[e] = atomicAdd(&hist[h[e]], 1);
}

__global__ void k_scanA(const int* __restrict__ hist, int* __restrict__ partial, int n) {
  __shared__ int sd[256];
  int base = blockIdx.x * 1024;
  int s = 0;
  for (int j = threadIdx.x; j < 1024; j += 256) {
    int idx = base + j;
    if (idx < n) s += hist[idx];
  }
  sd[threadIdx.x] = s;
  __syncthreads();
  for (int o = 128; o > 0; o >>= 1) {
    if (threadIdx.x < o) sd[threadIdx.x] += sd[threadIdx.x + o];
    __syncthreads();
  }
  if (threadIdx.x == 0) partial[blockIdx.x] = sd[0];
}

__global__ void k_scanB(int* __restrict__ partial, int nblk, int* __restrict__ row_ptr, int n) {
  if (threadIdx.x == 0 && blockIdx.x == 0) {
    int run = 0;
    for (int i = 0; i < nblk; i++) { int t = partial[i]; partial[i] = run; run += t; }
    row_ptr[n] = run;
  }
}

__global__ void k_scanC(const int* __restrict__ hist, const int* __restrict__ partial,
                        int* __restrict__ row_ptr, float* __restrict__ d_inv, int n) {
  __shared__ int sd[256];
  int t = threadIdx.x;
  int base = blockIdx.x * 1024 + t * 4;
  int v0 = 0, v1 = 0, v2 = 0, v3 = 0;
  if (base + 0 < n) v0 = hist[base + 0];
  if (base + 1 < n) v1 = hist[base + 1];
  if (base + 2 < n) v2 = hist[base + 2];
  if (base + 3 < n) v3 = hist[base + 3];
  int ts = v0 + v1 + v2 + v3;
  sd[t] = ts;
  __syncthreads();
  for (int o = 1; o < 256; o <<= 1) {
    int x = (t >= o) ? sd[t - o] : 0;
    __syncthreads();
    sd[t] += x;
    __syncthreads();
  }
  int run = partial[blockIdx.x] + sd[t] - ts;
  if (base + 0 < n) { row_ptr[base + 0] = run; run += v0; d_inv[base + 0] = 1.0f / sqrtf((float)v0); }
  if (base + 1 < n) { row_ptr[base + 1] = run; run += v1; d_inv[base + 1] = 1.0f / sqrtf((float)v1); }
  if (base + 2 < n) { row_ptr[base + 2] = run; run += v2; d_inv[base + 2] = 1.0f / sqrtf((float)v2); }
  if (base + 3 < n) { row_ptr[base + 3] = run; run += v3; d_inv[base + 3] = 1.0f / sqrtf((float)v3); }
}

__global__ void k_scatter(const int* __restrict__ h, const int* __restrict__ t,
                          const int* __restrict__ row_ptr, const int* __restrict__ rank,
                          const float* __restrict__ d_inv, uint2* __restrict__ edges, int E) {
  int e = blockIdx.x * 256 + threadIdx.x;
  if (e >= E) return;
  int hh = h[e], tt = t[e];
  int pos = row_ptr[hh] + rank[e];
  float g = d_inv[hh] * d_inv[tt];
  uint2 v; v.x = (unsigned)tt; v.y = __float_as_uint(g);
  edges[pos] = v;
}

__global__ void k_init(const float4* __restrict__ ue, const float4* __restrict__ ie,
                       float4* __restrict__ cur, float4* __restrict__ acc, int nU4, int nTot4) {
  int i = blockIdx.x * 256 + threadIdx.x;
  if (i >= nTot4) return;
  float4 v = (i < nU4) ? ue[i] : ie[i - nU4];
  cur[i] = v;
  acc[i] = v;
}

// wave per node; 8 gathers kept in flight (clamped addr + masked g so loads
// are unconditional -> compiler pipelines all 8 before the first waitcnt)
__global__ __launch_bounds__(256) void k_agg(const int* __restrict__ row_ptr,
                                             const uint2* __restrict__ edges,
                                             const float* __restrict__ cur,
                                             float* __restrict__ nxt,
                                             float* __restrict__ acc) {
  int node = (blockIdx.x << 2) + (threadIdx.x >> 6);
  int lane = threadIdx.x & 63;
  if (node >= NT) return;
  int s = row_ptr[node], e = row_ptr[node + 1];
  float sum = 0.f;
  for (int i = s; i < e; i += 8) {
    uint2 ed[8];
#pragma unroll
    for (int j = 0; j < 8; j++) {
      int idx = i + j;
      idx = idx < e ? idx : e - 1;  // deg >= 1 always (self-loops)
      ed[j] = edges[idx];
    }
    float c[8];
#pragma unroll
    for (int j = 0; j < 8; j++) c[j] = cur[(size_t)ed[j].x * 64 + lane];
#pragma unroll
    for (int j = 0; j < 8; j++) {
      float g = (i + j < e) ? __uint_as_float(ed[j].y) : 0.f;
      sum = fmaf(g, c[j], sum);
    }
  }
  int o = node * 64 + lane;
  nxt[o] = sum;
  acc[o] += sum;
}

__global__ __launch_bounds__(256) void k_kl(const float* __restrict__ acc,
                                            const float* __restrict__ lin_w,
                                            const float* __restrict__ lin_b,
                                            double* __restrict__ accums) {
  __shared__ float lw[64 * 33];
  __shared__ float lb[64];
  for (int i = threadIdx.x; i < 64 * 32; i += 256) lw[(i >> 5) * 33 + (i & 31)] = lin_w[i];
  if (threadIdx.x < 64) lb[threadIdx.x] = lin_b[threadIdx.x];
  __syncthreads();
  int lane = threadIdx.x & 63;
  int w = (blockIdx.x * 256 + threadIdx.x) >> 6;
  int nw = (gridDim.x * 256) >> 6;
  double dsum = 0.0;
  for (int row = w; row < NT; row += nw) {
    float m = acc[row * 64 + lane];
    float sp = softplusf(m);
    float sd = lb[lane] + 1e-8f;
#pragma unroll
    for (int j = 0; j < 32; j++) sd = fmaf(__shfl(sp, j, 64), lw[lane * 33 + j], sd);
    float e2 = expf(2.f * sd);
    float kl = -0.5f * (1.f + 2.f * sd - m * m - e2);
    if (!isfinite(kl)) kl = 0.f;
    float rs = wsum(kl);
    if (lane == 0) dsum += (double)rs;
  }
  if (lane == 0) atomicAdd(&accums[1], dsum);
}

__global__ __launch_bounds__(256) void k_batch_user(
    const float* __restrict__ acc, const float* __restrict__ user_emb,
    const float* __restrict__ eps, const float* __restrict__ intent,
    const float* __restrict__ lin_w, const float* __restrict__ lin_b,
    const int* __restrict__ users, const int* __restrict__ pos_items,
    const int* __restrict__ neg_items,
    float* __restrict__ gen_o, float* __restrict__ int_o, double* __restrict__ accums) {
  __shared__ float ui[64 * 130];
  __shared__ float lw[64 * 33];
  __shared__ float lb[64];
  __shared__ double red[8];
  for (int i = threadIdx.x; i < 64 * 128; i += 256) ui[(i >> 7) * 130 + (i & 127)] = intent[i];
  for (int i = threadIdx.x; i < 64 * 32; i += 256) lw[(i >> 5) * 33 + (i & 31)] = lin_w[i];
  if (threadIdx.x < 64) lb[threadIdx.x] = lin_b[threadIdx.x];
  __syncthreads();
  int lane = threadIdx.x & 63;
  int wid = threadIdx.x >> 6;
  int b = (blockIdx.x << 2) + wid;
  int u = users[b];
  float m = acc[u * 64 + lane];
  int k0 = lane * 2;
  float l0 = 0.f, l1 = 0.f;
  for (int d = 0; d < 64; d++) {
    float md = __shfl(m, d, 64);
    l0 = fmaf(md, ui[d * 130 + k0], l0);
    l1 = fmaf(md, ui[d * 130 + k0 + 1], l1);
  }
  float mx = wmax(fmaxf(l0, l1));
  float p0 = expf(l0 - mx), p1 = expf(l1 - mx);
  float tot = wsum(p0 + p1);
  p0 /= tot; p1 /= tot;
  float s = 0.f;
  for (int k = 0; k < 128; k++) {
    float pk = __shfl((k & 1) ? p1 : p0, k >> 1, 64);
    s = fmaf(pk, ui[lane * 130 + k], s);
  }
  float nrm = sqrtf(wsum(s * s));
  int_o[b * 64 + lane] = s / nrm;
  float sp = softplusf(m);
  float sd = lb[lane] + 1e-8f;
#pragma unroll
  for (int j = 0; j < 32; j++) sd = fmaf(__shfl(sp, j, 64), lw[lane * 33 + j], sd);
  float ge = m + eps[u * 64 + lane] * sd;
  float gn = sqrtf(wsum(ge * ge));
  gen_o[b * 64 + lane] = ge / gn;
  int pi = pos_items[b], ni = neg_items[b];
  float pv = acc[(NU + pi) * 64 + lane];
  float nv = acc[(NU + ni) * 64 + lane];
  float ps = wsum(m * pv);
  float ns = wsum(m * nv);
  float bpr = softplusf(ns - ps);
  float ue = user_emb[u * 64 + lane];
  float es = wsum(ue * ue);
  if (lane == 0) { red[wid] = (double)bpr; red[4 + wid] = (double)es; }
  __syncthreads();
  if (threadIdx.x == 0) {
    atomicAdd(&accums[0], red[0] + red[1] + red[2] + red[3]);
    atomicAdd(&accums[2], red[4] + red[5] + red[6] + red[7]);
  }
}

__global__ __launch_bounds__(256) void k_batch_item(
    const float* __restrict__ acc, const float* __restrict__ item_emb,
    const float* __restrict__ eps, const float* __restrict__ intent,
    const float* __restrict__ lin_w, const float* __restrict__ lin_b,
    const int* __restrict__ pos_items, const int* __restrict__ neg_items,
    float* __restrict__ gen_o, float* __restrict__ int_o, double* __restrict__ accums) {
  __shared__ float ui[64 * 130];
  __shared__ float lw[64 * 33];
  __shared__ float lb[64];
  __shared__ double red[4];
  for (int i = threadIdx.x; i < 64 * 128; i += 256) ui[(i >> 7) * 130 + (i & 127)] = intent[i];
  for (int i = threadIdx.x; i < 64 * 32; i += 256) lw[(i >> 5) * 33 + (i & 31)] = lin_w[i];
  if (threadIdx.x < 64) lb[threadIdx.x] = lin_b[threadIdx.x];
  __syncthreads();
  int lane = threadIdx.x & 63;
  int wid = threadIdx.x >> 6;
  int b = (blockIdx.x << 2) + wid;
  int pi = pos_items[b], ni = neg_items[b];
  int row = NU + pi;
  float m = acc[row * 64 + lane];
  int k0 = lane * 2;
  float l0 = 0.f, l1 = 0.f;
  for (int d = 0; d < 64; d++) {
    float md = __shfl(m, d, 64);
    l0 = fmaf(md, ui[d * 130 + k0], l0);
    l1 = fmaf(md, ui[d * 130 + k0 + 1], l1);
  }
  float mx = wmax(fmaxf(l0, l1));
  float p0 = expf(l0 - mx), p1 = expf(l1 - mx);
  float tot = wsum(p0 + p1);
  p0 /= tot; p1 /= tot;
  float s = 0.f;
  for (int k = 0; k < 128; k++) {
    float pk = __shfl((k & 1) ? p1 : p0, k >> 1, 64);
    s = fmaf(pk, ui[lane * 130 + k], s);
  }
  float nrm = sqrtf(wsum(s * s));
  int_o[b * 64 + lane] = s / nrm;
  float sp = softplusf(m);
  float sd = lb[lane] + 1e-8f;
#pragma unroll
  for (int j = 0; j < 32; j++) sd = fmaf(__shfl(sp, j, 64), lw[lane * 33 + j], sd);
  float ge = m + eps[row * 64 + lane] * sd;
  float gn = sqrtf(wsum(ge * ge));
  gen_o[b * 64 + lane] = ge / gn;
  float a0 = item_emb[pi * 64 + lane];
  float a1 = item_emb[ni * 64 + lane];
  float es = wsum(a0 * a0 + a1 * a1);
  if (lane == 0) red[wid] = (double)es;
  __syncthreads();
  if (threadIdx.x == 0) atomicAdd(&accums[2], red[0] + red[1] + red[2] + red[3]);
}

__global__ void k_int(const float* __restrict__ ui, const float* __restrict__ ii,
                      double* __restrict__ accums) {
  float s = 0.f;
  for (int i = threadIdx.x; i < 64 * 128; i += 256) {
    float a = ui[i], b = ii[i];
    s = fmaf(a, a, s);
    s = fmaf(b, b, s);
  }
  s = wsum(s);
  __shared__ float red[4];
  if ((threadIdx.x & 63) == 0) red[threadIdx.x >> 6] = s;
  __syncthreads();
  if (threadIdx.x == 0) atomicAdd(&accums[3], (double)(red[0] + red[1] + red[2] + red[3]));
}

// neg_i = sum_j exp(dot(e1_i, e2_j)/TEMP); grid (64 i-tiles, 32 = pair*16 + q)
__global__ __launch_bounds__(64) void k_nce_neg(
    const float* __restrict__ ugen, const float* __restrict__ uio,
    const float* __restrict__ igen, const float* __restrict__ iio,
    float* __restrict__ negu, float* __restrict__ negi) {
  __shared__ __align__(16) float tile[4096];
  int pair = blockIdx.y >> 4, q = blockIdx.y & 15;
  const float* e1 = pair ? igen : ugen;
  const float* e2 = pair ? iio : uio;
  float* nego = pair ? negi : negu;
  int lane = threadIdx.x;
  int i = blockIdx.x * 64 + lane;
  const float4* e14 = (const float4*)(e1 + (size_t)i * 64);
  float4 r[16];
#pragma unroll
  for (int w = 0; w < 16; w++) r[w] = e14[w];
  const float4* t4 = (const float4*)tile;
  const float4* e24 = (const float4*)e2;
  float nsum = 0.f;
  for (int jt = 0; jt < 4; jt++) {
    int j0 = q * 256 + jt * 64;
    __syncthreads();
    for (int w = lane; w < 1024; w += 64) ((float4*)tile)[w] = e24[j0 * 16 + w];
    __syncthreads();
    for (int jj = 0; jj < 64; jj++) {
      float dot = 0.f;
#pragma unroll
      for (int w = 0; w < 16; w++) {
        float4 t = t4[jj * 16 + w];
        dot = fmaf(r[w].x, t.x, dot);
        dot = fmaf(r[w].y, t.y, dot);
        dot = fmaf(r[w].z, t.z, dot);
        dot = fmaf(r[w].w, t.w, dot);
      }
      nsum += expf(dot * 5.0f);
    }
  }
  atomicAdd(&nego[i], nsum);
}

__global__ __launch_bounds__(256) void k_nce_final(
    const float* __restrict__ ugen, const float* __restrict__ uio,
    const float* __restrict__ igen, const float* __restrict__ iio,
    const float* __restrict__ negu, const float* __restrict__ negi,
    double* __restrict__ accums) {
  __shared__ double red[4];
  int lane = threadIdx.x & 63, wid = threadIdx.x >> 6;
  int w = blockIdx.x * 4 + wid;
  int pair = w >> 12, i = w & 4095;
  const float* e1 = pair ? igen : ugen;
  const float* e2 = pair ? iio : uio;
  const float* ng = pair ? negi : negu;
  float dot = wsum(e1[i * 64 + lane] * e2[i * 64 + lane]);
  if (lane == 0) {
    float pos = expf(dot * 5.f);
    red[wid] = (double)(-logf(pos / (ng[i] + 1e-8f) + 1e-8f));
  }
  __syncthreads();
  if (threadIdx.x == 0) atomicAdd(&accums[4], red[0] + red[1] + red[2] + red[3]);
}

__global__ void k_fin(const double* __restrict__ accums, float* __restrict__ out) {
  if (threadIdx.x == 0 && blockIdx.x == 0) {
    double bpr = accums[0] / (double)BB;
    double kl = 0.01 * accums[1] / (double)NT;
    out[0] = (float)(bpr + kl);
    out[1] = (float)(0.1 * accums[4] / (double)BB);
    out[2] = (float)(1e-5 * accums[2]);
    out[3] = (float)(1e-5 * accums[3]);
  }
}

extern "C" void kernel_launch(void* const* d_in, const int* in_sizes, int n_in,
                              void* d_out, int out_size, void* d_ws, size_t ws_size,
                              hipStream_t stream) {
  const float* user_emb = (const float*)d_in[0];
  const float* item_emb = (const float*)d_in[1];
  const float* user_int = (const float*)d_in[2];
  const float* item_int = (const float*)d_in[3];
  const float* lin_w = (const float*)d_in[4];
  const float* lin_b = (const float*)d_in[5];
  const float* eps = (const float*)d_in[6];
  const int* h_list = (const int*)d_in[7];
  const int* t_list = (const int*)d_in[8];
  const int* users = (const int*)d_in[9];
  const int* pos_items = (const int*)d_in[10];
  const int* neg_items = (const int*)d_in[11];
  float* out = (float*)d_out;
  const int E = in_sizes[7];

  char* ws = (char*)d_ws;
  size_t off = 0;
  auto take = [&](size_t bytes) -> char* {
    char* p = ws + off;
    off = (off + bytes + 255) & ~(size_t)255;
    return p;
  };
  int* hist = (int*)take((size_t)NT * 4);
  int* row_ptr = (int*)take((size_t)(NT + 1) * 4);
  float* d_inv = (float*)take((size_t)NT * 4);
  int* partial = (int*)take(1024);
  uint2* edges = (uint2*)take((size_t)E * 8);
  float* bufA = (float*)take((size_t)NT * 64 * 4);
  float* bufB = (float*)take((size_t)NT * 64 * 4);
  float* acc = (float*)take((size_t)NT * 64 * 4);
  float* ugen = (float*)take((size_t)BB * 64 * 4);
  float* igen = (float*)take((size_t)BB * 64 * 4);
  float* uio = (float*)take((size_t)BB * 64 * 4);
  float* iio = (float*)take((size_t)BB * 64 * 4);
  float* negu = (float*)take((size_t)BB * 4);
  float* negi = (float*)take((size_t)BB * 4);
  double* accums = (double*)take(64);
  if (off > ws_size) return;
  // rank[] (E ints) aliases bufB: dead before first k_agg writes bufB
  int* rank = (int*)bufB;

  hipMemsetAsync(hist, 0, (size_t)NT * 4, stream);
  hipMemsetAsync(negu, 0, (size_t)BB * 4, stream);
  hipMemsetAsync(negi, 0, (size_t)BB * 4, stream);
  hipMemsetAsync(accums, 0, 64, stream);

  int gridE = (E + 255) / 256;
  int nblk = (NT + 1023) / 1024;
  k_hist<<<gridE, 256, 0, stream>>>(h_list, hist, rank, E);
  k_scanA<<<nblk, 256, 0, stream>>>(hist, partial, NT);
  k_scanB<<<1, 64, 0, stream>>>(partial, nblk, row_ptr, NT);
  k_scanC<<<nblk, 256, 0, stream>>>(hist, partial, row_ptr, d_inv, NT);
  k_scatter<<<gridE, 256, 0, stream>>>(h_list, t_list, row_ptr, rank, d_inv, edges, E);

  int nU4 = NU * 16, nTot4 = NT * 16;
  k_init<<<(nTot4 + 255) / 256, 256, 0, stream>>>((const float4*)user_emb, (const float4*)item_emb,
                                                  (float4*)bufA, (float4*)acc, nU4, nTot4);
  int gridAgg = (NT + 3) / 4;
  k_agg<<<gridAgg, 256, 0, stream>>>(row_ptr, edges, bufA, bufB, acc);
  k_agg<<<gridAgg, 256, 0, stream>>>(row_ptr, edges, bufB, bufA, acc);
  k_agg<<<gridAgg, 256, 0, stream>>>(row_ptr, edges, bufA, bufB, acc);

  k_kl<<<512, 256, 0, stream>>>(acc, lin_w, lin_b, accums);
  k_batch_user<<<BB / 4, 256, 0, stream>>>(acc, user_emb, eps, user_int, lin_w, lin_b,
                                           users, pos_items, neg_items, ugen, uio, accums);
  k_batch_item<<<BB / 4, 256, 0, stream>>>(acc, item_emb, eps, item_int, lin_w, lin_b,
                                           pos_items, neg_items, igen, iio, accums);
  k_int<<<1, 256, 0, stream>>>(user_int, item_int, accums);
  k_nce_neg<<<dim3(64, 32), 64, 0, stream>>>(ugen, uio, igen, iio, negu, negi);
  k_nce_final<<<(2 * BB) / 4, 256, 0, stream>>>(ugen, uio, igen, iio, negu, negi, accums);
  k_fin<<<1, 64, 0, stream>>>(accums, out);
}

// Round 3
// 1071.489 us; speedup vs baseline: 1.2767x; 1.0559x over previous
//
#include <hip/hip_runtime.h>

#define NU 50000
#define NI 100000
#define NT 150000
#define BB 4096

__device__ __forceinline__ float softplusf(float x) {
  return fmaxf(x, 0.f) + log1pf(expf(-fabsf(x)));
}
__device__ __forceinline__ float wsum(float v) {
#pragma unroll
  for (int o = 32; o > 0; o >>= 1) v += __shfl_xor(v, o, 64);
  return v;
}
__device__ __forceinline__ float wmax(float v) {
#pragma unroll
  for (int o = 32; o > 0; o >>= 1) v = fmaxf(v, __shfl_xor(v, o, 64));
  return v;
}

// hist + per-edge rank in one pass
__global__ void k_hist(const int* __restrict__ h, int* __restrict__ hist,
                       int* __restrict__ rank, int E) {
  int e = blockIdx.x * 256 + threadIdx.x;
  if (e < E) rank[e] = atomicAdd(&hist[h[e]], 1);
}

// per-1024-chunk sums of PADDED degrees (pad each node's count to multiple of 8)
__global__ void k_scanA(const int* __restrict__ hist, int* __restrict__ partial, int n) {
  __shared__ int sd[256];
  int base = blockIdx.x * 1024;
  int s = 0;
  for (int j = threadIdx.x; j < 1024; j += 256) {
    int idx = base + j;
    if (idx < n) s += (hist[idx] + 7) & ~7;
  }
  sd[threadIdx.x] = s;
  __syncthreads();
  for (int o = 128; o > 0; o >>= 1) {
    if (threadIdx.x < o) sd[threadIdx.x] += sd[threadIdx.x + o];
    __syncthreads();
  }
  if (threadIdx.x == 0) partial[blockIdx.x] = sd[0];
}

// single-block exclusive scan over partials (nblk <= 256)
__global__ void k_scanB(int* __restrict__ partial, int nblk, int* __restrict__ row_ptr, int n) {
  __shared__ int sd[256];
  int t = threadIdx.x;
  int v = (t < nblk) ? partial[t] : 0;
  sd[t] = v;
  __syncthreads();
  for (int o = 1; o < 256; o <<= 1) {
    int x = (t >= o) ? sd[t - o] : 0;
    __syncthreads();
    sd[t] += x;
    __syncthreads();
  }
  if (t < nblk) partial[t] = sd[t] - v;  // exclusive
  if (t == nblk - 1) row_ptr[n] = sd[t]; // total padded edges
}

__global__ void k_scanC(const int* __restrict__ hist, const int* __restrict__ partial,
                        int* __restrict__ row_ptr, float* __restrict__ d_inv, int n) {
  __shared__ int sd[256];
  int t = threadIdx.x;
  int base = blockIdx.x * 1024 + t * 4;
  int v0 = 0, v1 = 0, v2 = 0, v3 = 0;
  if (base + 0 < n) v0 = hist[base + 0];
  if (base + 1 < n) v1 = hist[base + 1];
  if (base + 2 < n) v2 = hist[base + 2];
  if (base + 3 < n) v3 = hist[base + 3];
  int p0 = (v0 + 7) & ~7, p1 = (v1 + 7) & ~7, p2 = (v2 + 7) & ~7, p3 = (v3 + 7) & ~7;
  int ts = p0 + p1 + p2 + p3;
  sd[t] = ts;
  __syncthreads();
  for (int o = 1; o < 256; o <<= 1) {
    int x = (t >= o) ? sd[t - o] : 0;
    __syncthreads();
    sd[t] += x;
    __syncthreads();
  }
  int run = partial[blockIdx.x] + sd[t] - ts;
  if (base + 0 < n) { row_ptr[base + 0] = run; run += p0; d_inv[base + 0] = 1.0f / sqrtf((float)v0); }
  if (base + 1 < n) { row_ptr[base + 1] = run; run += p1; d_inv[base + 1] = 1.0f / sqrtf((float)v1); }
  if (base + 2 < n) { row_ptr[base + 2] = run; run += p2; d_inv[base + 2] = 1.0f / sqrtf((float)v2); }
  if (base + 3 < n) { row_ptr[base + 3] = run; run += p3; d_inv[base + 3] = 1.0f / sqrtf((float)v3); }
}

__global__ void k_scatter(const int* __restrict__ h, const int* __restrict__ t,
                          const int* __restrict__ row_ptr, const int* __restrict__ rank,
                          const float* __restrict__ d_inv, uint2* __restrict__ edges, int E) {
  int e = blockIdx.x * 256 + threadIdx.x;
  if (e >= E) return;
  int hh = h[e], tt = t[e];
  int pos = row_ptr[hh] + rank[e];
  float g = d_inv[hh] * d_inv[tt];
  uint2 v; v.x = (unsigned)tt; v.y = __float_as_uint(g);
  edges[pos] = v;
}

__global__ void k_init(const float4* __restrict__ ue, const float4* __restrict__ ie,
                       float4* __restrict__ cur, float4* __restrict__ acc, int nU4, int nTot4) {
  int i = blockIdx.x * 256 + threadIdx.x;
  if (i >= nTot4) return;
  float4 v = (i < nU4) ? ue[i] : ie[i - nU4];
  cur[i] = v;
  acc[i] = v;
}

// wave per node; edge lists padded to x8 with (idx=0,g=0) -> fully branchless.
// 32-bit addressing; edge records fetched as 2x dwordx4 per 8 edges.
__global__ __launch_bounds__(256) void k_agg(const int* __restrict__ row_ptr,
                                             const uint2* __restrict__ edges,
                                             const float* __restrict__ cur,
                                             float* __restrict__ nxt,
                                             float* __restrict__ acc) {
  int node = (blockIdx.x << 2) + (threadIdx.x >> 6);
  unsigned lane = threadIdx.x & 63;
  int s = row_ptr[node], e = row_ptr[node + 1];
  float sum = 0.f;
  for (int i = s; i < e; i += 8) {
    const uint4* e4 = (const uint4*)(edges + i);
    uint4 A = e4[0], B = e4[1], C = e4[2], D = e4[3];
    float c0 = cur[(A.x << 6) + lane];
    float c1 = cur[(A.z << 6) + lane];
    float c2 = cur[(B.x << 6) + lane];
    float c3 = cur[(B.z << 6) + lane];
    float c4 = cur[(C.x << 6) + lane];
    float c5 = cur[(C.z << 6) + lane];
    float c6 = cur[(D.x << 6) + lane];
    float c7 = cur[(D.z << 6) + lane];
    sum = fmaf(__uint_as_float(A.y), c0, sum);
    sum = fmaf(__uint_as_float(A.w), c1, sum);
    sum = fmaf(__uint_as_float(B.y), c2, sum);
    sum = fmaf(__uint_as_float(B.w), c3, sum);
    sum = fmaf(__uint_as_float(C.y), c4, sum);
    sum = fmaf(__uint_as_float(C.w), c5, sum);
    sum = fmaf(__uint_as_float(D.y), c6, sum);
    sum = fmaf(__uint_as_float(D.w), c7, sum);
  }
  unsigned o = ((unsigned)node << 6) + lane;
  nxt[o] = sum;
  acc[o] += sum;
}

__global__ __launch_bounds__(256) void k_kl(const float* __restrict__ acc,
                                            const float* __restrict__ lin_w,
                                            const float* __restrict__ lin_b,
                                            double* __restrict__ accums) {
  __shared__ float lw[64 * 33];
  __shared__ float lb[64];
  for (int i = threadIdx.x; i < 64 * 32; i += 256) lw[(i >> 5) * 33 + (i & 31)] = lin_w[i];
  if (threadIdx.x < 64) lb[threadIdx.x] = lin_b[threadIdx.x];
  __syncthreads();
  int lane = threadIdx.x & 63;
  int w = (blockIdx.x * 256 + threadIdx.x) >> 6;
  int nw = (gridDim.x * 256) >> 6;
  double dsum = 0.0;
  for (int row = w; row < NT; row += nw) {
    float m = acc[row * 64 + lane];
    float sp = softplusf(m);
    float sd = lb[lane] + 1e-8f;
#pragma unroll
    for (int j = 0; j < 32; j++) sd = fmaf(__shfl(sp, j, 64), lw[lane * 33 + j], sd);
    float e2 = expf(2.f * sd);
    float kl = -0.5f * (1.f + 2.f * sd - m * m - e2);
    if (!isfinite(kl)) kl = 0.f;
    float rs = wsum(kl);
    if (lane == 0) dsum += (double)rs;
  }
  if (lane == 0) atomicAdd(&accums[1], dsum);
}

__global__ __launch_bounds__(256) void k_batch_user(
    const float* __restrict__ acc, const float* __restrict__ user_emb,
    const float* __restrict__ eps, const float* __restrict__ intent,
    const float* __restrict__ lin_w, const float* __restrict__ lin_b,
    const int* __restrict__ users, const int* __restrict__ pos_items,
    const int* __restrict__ neg_items,
    float* __restrict__ gen_o, float* __restrict__ int_o, double* __restrict__ accums) {
  __shared__ float ui[64 * 130];
  __shared__ float lw[64 * 33];
  __shared__ float lb[64];
  __shared__ double red[8];
  for (int i = threadIdx.x; i < 64 * 128; i += 256) ui[(i >> 7) * 130 + (i & 127)] = intent[i];
  for (int i = threadIdx.x; i < 64 * 32; i += 256) lw[(i >> 5) * 33 + (i & 31)] = lin_w[i];
  if (threadIdx.x < 64) lb[threadIdx.x] = lin_b[threadIdx.x];
  __syncthreads();
  int lane = threadIdx.x & 63;
  int wid = threadIdx.x >> 6;
  int b = (blockIdx.x << 2) + wid;
  int u = users[b];
  float m = acc[u * 64 + lane];
  int k0 = lane * 2;
  float l0 = 0.f, l1 = 0.f;
  for (int d = 0; d < 64; d++) {
    float md = __shfl(m, d, 64);
    l0 = fmaf(md, ui[d * 130 + k0], l0);
    l1 = fmaf(md, ui[d * 130 + k0 + 1], l1);
  }
  float mx = wmax(fmaxf(l0, l1));
  float p0 = expf(l0 - mx), p1 = expf(l1 - mx);
  float tot = wsum(p0 + p1);
  p0 /= tot; p1 /= tot;
  float s = 0.f;
  for (int k = 0; k < 128; k++) {
    float pk = __shfl((k & 1) ? p1 : p0, k >> 1, 64);
    s = fmaf(pk, ui[lane * 130 + k], s);
  }
  float nrm = sqrtf(wsum(s * s));
  int_o[b * 64 + lane] = s / nrm;
  float sp = softplusf(m);
  float sd = lb[lane] + 1e-8f;
#pragma unroll
  for (int j = 0; j < 32; j++) sd = fmaf(__shfl(sp, j, 64), lw[lane * 33 + j], sd);
  float ge = m + eps[u * 64 + lane] * sd;
  float gn = sqrtf(wsum(ge * ge));
  gen_o[b * 64 + lane] = ge / gn;
  int pi = pos_items[b], ni = neg_items[b];
  float pv = acc[(NU + pi) * 64 + lane];
  float nv = acc[(NU + ni) * 64 + lane];
  float ps = wsum(m * pv);
  float ns = wsum(m * nv);
  float bpr = softplusf(ns - ps);
  float ue = user_emb[u * 64 + lane];
  float es = wsum(ue * ue);
  if (lane == 0) { red[wid] = (double)bpr; red[4 + wid] = (double)es; }
  __syncthreads();
  if (threadIdx.x == 0) {
    atomicAdd(&accums[0], red[0] + red[1] + red[2] + red[3]);
    atomicAdd(&accums[2], red[4] + red[5] + red[6] + red[7]);
  }
}

__global__ __launch_bounds__(256) void k_batch_item(
    const float* __restrict__ acc, const float* __restrict__ item_emb,
    const float* __restrict__ eps, const float* __restrict__ intent,
    const float* __restrict__ lin_w, const float* __restrict__ lin_b,
    const int* __restrict__ pos_items, const int* __restrict__ neg_items,
    float* __restrict__ gen_o, float* __restrict__ int_o, double* __restrict__ accums) {
  __shared__ float ui[64 * 130];
  __shared__ float lw[64 * 33];
  __shared__ float lb[64];
  __shared__ double red[4];
  for (int i = threadIdx.x; i < 64 * 128; i += 256) ui[(i >> 7) * 130 + (i & 127)] = intent[i];
  for (int i = threadIdx.x; i < 64 * 32; i += 256) lw[(i >> 5) * 33 + (i & 31)] = lin_w[i];
  if (threadIdx.x < 64) lb[threadIdx.x] = lin_b[threadIdx.x];
  __syncthreads();
  int lane = threadIdx.x & 63;
  int wid = threadIdx.x >> 6;
  int b = (blockIdx.x << 2) + wid;
  int pi = pos_items[b], ni = neg_items[b];
  int row = NU + pi;
  float m = acc[row * 64 + lane];
  int k0 = lane * 2;
  float l0 = 0.f, l1 = 0.f;
  for (int d = 0; d < 64; d++) {
    float md = __shfl(m, d, 64);
    l0 = fmaf(md, ui[d * 130 + k0], l0);
    l1 = fmaf(md, ui[d * 130 + k0 + 1], l1);
  }
  float mx = wmax(fmaxf(l0, l1));
  float p0 = expf(l0 - mx), p1 = expf(l1 - mx);
  float tot = wsum(p0 + p1);
  p0 /= tot; p1 /= tot;
  float s = 0.f;
  for (int k = 0; k < 128; k++) {
    float pk = __shfl((k & 1) ? p1 : p0, k >> 1, 64);
    s = fmaf(pk, ui[lane * 130 + k], s);
  }
  float nrm = sqrtf(wsum(s * s));
  int_o[b * 64 + lane] = s / nrm;
  float sp = softplusf(m);
  float sd = lb[lane] + 1e-8f;
#pragma unroll
  for (int j = 0; j < 32; j++) sd = fmaf(__shfl(sp, j, 64), lw[lane * 33 + j], sd);
  float ge = m + eps[row * 64 + lane] * sd;
  float gn = sqrtf(wsum(ge * ge));
  gen_o[b * 64 + lane] = ge / gn;
  float a0 = item_emb[pi * 64 + lane];
  float a1 = item_emb[ni * 64 + lane];
  float es = wsum(a0 * a0 + a1 * a1);
  if (lane == 0) red[wid] = (double)es;
  __syncthreads();
  if (threadIdx.x == 0) atomicAdd(&accums[2], red[0] + red[1] + red[2] + red[3]);
}

__global__ void k_int(const float* __restrict__ ui, const float* __restrict__ ii,
                      double* __restrict__ accums) {
  float s = 0.f;
  for (int i = threadIdx.x; i < 64 * 128; i += 256) {
    float a = ui[i], b = ii[i];
    s = fmaf(a, a, s);
    s = fmaf(b, b, s);
  }
  s = wsum(s);
  __shared__ float red[4];
  if ((threadIdx.x & 63) == 0) red[threadIdx.x >> 6] = s;
  __syncthreads();
  if (threadIdx.x == 0) atomicAdd(&accums[3], (double)(red[0] + red[1] + red[2] + red[3]));
}

__global__ __launch_bounds__(64) void k_nce_neg(
    const float* __restrict__ ugen, const float* __restrict__ uio,
    const float* __restrict__ igen, const float* __restrict__ iio,
    float* __restrict__ negu, float* __restrict__ negi) {
  __shared__ __align__(16) float tile[4096];
  int pair = blockIdx.y >> 4, q = blockIdx.y & 15;
  const float* e1 = pair ? igen : ugen;
  const float* e2 = pair ? iio : uio;
  float* nego = pair ? negi : negu;
  int lane = threadIdx.x;
  int i = blockIdx.x * 64 + lane;
  const float4* e14 = (const float4*)(e1 + (size_t)i * 64);
  float4 r[16];
#pragma unroll
  for (int w = 0; w < 16; w++) r[w] = e14[w];
  const float4* t4 = (const float4*)tile;
  const float4* e24 = (const float4*)e2;
  float nsum = 0.f;
  for (int jt = 0; jt < 4; jt++) {
    int j0 = q * 256 + jt * 64;
    __syncthreads();
    for (int w = lane; w < 1024; w += 64) ((float4*)tile)[w] = e24[j0 * 16 + w];
    __syncthreads();
    for (int jj = 0; jj < 64; jj++) {
      float dot = 0.f;
#pragma unroll
      for (int w = 0; w < 16; w++) {
        float4 t = t4[jj * 16 + w];
        dot = fmaf(r[w].x, t.x, dot);
        dot = fmaf(r[w].y, t.y, dot);
        dot = fmaf(r[w].z, t.z, dot);
        dot = fmaf(r[w].w, t.w, dot);
      }
      nsum += expf(dot * 5.0f);
    }
  }
  atomicAdd(&nego[i], nsum);
}

__global__ __launch_bounds__(256) void k_nce_final(
    const float* __restrict__ ugen, const float* __restrict__ uio,
    const float* __restrict__ igen, const float* __restrict__ iio,
    const float* __restrict__ negu, const float* __restrict__ negi,
    double* __restrict__ accums) {
  __shared__ double red[4];
  int lane = threadIdx.x & 63, wid = threadIdx.x >> 6;
  int w = blockIdx.x * 4 + wid;
  int pair = w >> 12, i = w & 4095;
  const float* e1 = pair ? igen : ugen;
  const float* e2 = pair ? iio : uio;
  const float* ng = pair ? negi : negu;
  float dot = wsum(e1[i * 64 + lane] * e2[i * 64 + lane]);
  if (lane == 0) {
    float pos = expf(dot * 5.f);
    red[wid] = (double)(-logf(pos / (ng[i] + 1e-8f) + 1e-8f));
  }
  __syncthreads();
  if (threadIdx.x == 0) atomicAdd(&accums[4], red[0] + red[1] + red[2] + red[3]);
}

__global__ void k_fin(const double* __restrict__ accums, float* __restrict__ out) {
  if (threadIdx.x == 0 && blockIdx.x == 0) {
    double bpr = accums[0] / (double)BB;
    double kl = 0.01 * accums[1] / (double)NT;
    out[0] = (float)(bpr + kl);
    out[1] = (float)(0.1 * accums[4] / (double)BB);
    out[2] = (float)(1e-5 * accums[2]);
    out[3] = (float)(1e-5 * accums[3]);
  }
}

extern "C" void kernel_launch(void* const* d_in, const int* in_sizes, int n_in,
                              void* d_out, int out_size, void* d_ws, size_t ws_size,
                              hipStream_t stream) {
  const float* user_emb = (const float*)d_in[0];
  const float* item_emb = (const float*)d_in[1];
  const float* user_int = (const float*)d_in[2];
  const float* item_int = (const float*)d_in[3];
  const float* lin_w = (const float*)d_in[4];
  const float* lin_b = (const float*)d_in[5];
  const float* eps = (const float*)d_in[6];
  const int* h_list = (const int*)d_in[7];
  const int* t_list = (const int*)d_in[8];
  const int* users = (const int*)d_in[9];
  const int* pos_items = (const int*)d_in[10];
  const int* neg_items = (const int*)d_in[11];
  float* out = (float*)d_out;
  const int E = in_sizes[7];
  const size_t Ecap = (size_t)E + 8 * (size_t)NT;  // padded-edge capacity

  char* ws = (char*)d_ws;
  size_t off = 0;
  auto take = [&](size_t bytes) -> char* {
    char* p = ws + off;
    off = (off + bytes + 255) & ~(size_t)255;
    return p;
  };
  int* hist = (int*)take((size_t)NT * 4);
  int* row_ptr = (int*)take((size_t)(NT + 1) * 4);
  float* d_inv = (float*)take((size_t)NT * 4);
  int* partial = (int*)take(1024);
  uint2* edges = (uint2*)take(Ecap * 8);
  float* bufA = (float*)take((size_t)NT * 64 * 4);
  float* bufB = (float*)take((size_t)NT * 64 * 4);
  float* acc = (float*)take((size_t)NT * 64 * 4);
  float* ugen = (float*)take((size_t)BB * 64 * 4);
  float* igen = (float*)take((size_t)BB * 64 * 4);
  float* uio = (float*)take((size_t)BB * 64 * 4);
  float* iio = (float*)take((size_t)BB * 64 * 4);
  float* negu = (float*)take((size_t)BB * 4);
  float* negi = (float*)take((size_t)BB * 4);
  double* accums = (double*)take(64);
  if (off > ws_size) return;
  // rank[] (E ints) aliases bufB: dead before first k_agg writes bufB
  int* rank = (int*)bufB;

  hipMemsetAsync(hist, 0, (size_t)NT * 4, stream);
  hipMemsetAsync(edges, 0, Ecap * 8, stream);  // pad entries read row 0 with g=0
  hipMemsetAsync(negu, 0, (size_t)BB * 4, stream);
  hipMemsetAsync(negi, 0, (size_t)BB * 4, stream);
  hipMemsetAsync(accums, 0, 64, stream);

  int gridE = (E + 255) / 256;
  int nblk = (NT + 1023) / 1024;  // 147
  k_hist<<<gridE, 256, 0, stream>>>(h_list, hist, rank, E);
  k_scanA<<<nblk, 256, 0, stream>>>(hist, partial, NT);
  k_scanB<<<1, 256, 0, stream>>>(partial, nblk, row_ptr, NT);
  k_scanC<<<nblk, 256, 0, stream>>>(hist, partial, row_ptr, d_inv, NT);
  k_scatter<<<gridE, 256, 0, stream>>>(h_list, t_list, row_ptr, rank, d_inv, edges, E);

  int nU4 = NU * 16, nTot4 = NT * 16;
  k_init<<<(nTot4 + 255) / 256, 256, 0, stream>>>((const float4*)user_emb, (const float4*)item_emb,
                                                  (float4*)bufA, (float4*)acc, nU4, nTot4);
  int gridAgg = NT / 4;
  k_agg<<<gridAgg, 256, 0, stream>>>(row_ptr, edges, bufA, bufB, acc);
  k_agg<<<gridAgg, 256, 0, stream>>>(row_ptr, edges, bufB, bufA, acc);
  k_agg<<<gridAgg, 256, 0, stream>>>(row_ptr, edges, bufA, bufB, acc);

  k_kl<<<512, 256, 0, stream>>>(acc, lin_w, lin_b, accums);
  k_batch_user<<<BB / 4, 256, 0, stream>>>(acc, user_emb, eps, user_int, lin_w, lin_b,
                                           users, pos_items, neg_items, ugen, uio, accums);
  k_batch_item<<<BB / 4, 256, 0, stream>>>(acc, item_emb, eps, item_int, lin_w, lin_b,
                                           pos_items, neg_items, igen, iio, accums);
  k_int<<<1, 256, 0, stream>>>(user_int, item_int, accums);
  k_nce_neg<<<dim3(64, 32), 64, 0, stream>>>(ugen, uio, igen, iio, negu, negi);
  k_nce_final<<<(2 * BB) / 4, 256, 0, stream>>>(ugen, uio, igen, iio, negu, negi, accums);
  k_fin<<<1, 64, 0, stream>>>(accums, out);
}

// Round 4
// 928.756 us; speedup vs baseline: 1.4729x; 1.1537x over previous
//
#include <hip/hip_runtime.h>

#define NU 50000
#define NI 100000
#define NT 150000
#define BB 4096
#define NBUCK 147   // ceil(NT/1024)
#define BCAP 24576  // per-bucket edge capacity: mean 21504, sd ~143 -> +21 sigma

typedef __attribute__((ext_vector_type(8))) short bf16x8;
typedef __attribute__((ext_vector_type(4))) float f32x4;

__device__ __forceinline__ float softplusf(float x) {
  return fmaxf(x, 0.f) + log1pf(expf(-fabsf(x)));
}
__device__ __forceinline__ float wsum(float v) {
#pragma unroll
  for (int o = 32; o > 0; o >>= 1) v += __shfl_xor(v, o, 64);
  return v;
}
__device__ __forceinline__ float wmax(float v) {
#pragma unroll
  for (int o = 32; o > 0; o >>= 1) v = fmaxf(v, __shfl_xor(v, o, 64));
  return v;
}
__device__ __forceinline__ unsigned short f2b(float x) {
  unsigned u = __float_as_uint(x);
  return (unsigned short)((u + 0x7FFFu + ((u >> 16) & 1u)) >> 16);
}

// ---------------- CSR build: two-level bucket partition ----------------
// Level 1: partition edges into NBUCK coarse buckets (h >> 10) using LDS
// histograms; one global atomic per (block,bucket) to reserve space.
__global__ __launch_bounds__(256) void k_part(const int* __restrict__ h,
                                              int* __restrict__ gcur,
                                              uint2* __restrict__ part, int E) {
  __shared__ int cnt[NBUCK];
  __shared__ int base[NBUCK];
  for (int b = threadIdx.x; b < NBUCK; b += 256) cnt[b] = 0;
  __syncthreads();
  int e0 = blockIdx.x * 4096 + threadIdx.x * 16;
  int nval = E - e0;
  nval = nval < 0 ? 0 : (nval > 16 ? 16 : nval);
  int hh[16];
  if (nval == 16) {
    const int4* hp = (const int4*)(h + e0);
#pragma unroll
    for (int j = 0; j < 4; j++) {
      int4 v = hp[j];
      hh[j * 4] = v.x; hh[j * 4 + 1] = v.y; hh[j * 4 + 2] = v.z; hh[j * 4 + 3] = v.w;
    }
  } else {
    for (int j = 0; j < nval; j++) hh[j] = h[e0 + j];
  }
  for (int j = 0; j < nval; j++) atomicAdd(&cnt[hh[j] >> 10], 1);
  __syncthreads();
  for (int b = threadIdx.x; b < NBUCK; b += 256) {
    int c = cnt[b];
    base[b] = c ? atomicAdd(&gcur[b], c) : 0;
    cnt[b] = 0;
  }
  __syncthreads();
  for (int j = 0; j < nval; j++) {
    int b = hh[j] >> 10;
    int r = atomicAdd(&cnt[b], 1);
    uint2 v; v.x = (unsigned)hh[j]; v.y = (unsigned)(e0 + j);
    part[(size_t)b * BCAP + base[b] + r] = v;
  }
}

// Level 2a: per-bucket exact node counts -> deg, d_inv, padded bucket total
__global__ __launch_bounds__(256) void k_csr_count(const uint2* __restrict__ part,
                                                   const int* __restrict__ gcur,
                                                   int* __restrict__ ncnt_g,
                                                   float* __restrict__ d_inv,
                                                   int* __restrict__ btot) {
  __shared__ int ncnt[1024];
  __shared__ int sd[256];
  int b = blockIdx.x, tid = threadIdx.x;
  int n0 = b << 10;
  int nn = NT - n0; if (nn > 1024) nn = 1024;
  for (int i = tid; i < 1024; i += 256) ncnt[i] = 0;
  __syncthreads();
  int m = gcur[b];
  const uint2* p = part + (size_t)b * BCAP;
  for (int i = tid; i < m; i += 256) atomicAdd(&ncnt[p[i].x & 1023], 1);
  __syncthreads();
  int s = 0;
#pragma unroll
  for (int j = 0; j < 4; j++) {
    int idx = tid * 4 + j;
    int c = ncnt[idx];
    if (idx < nn) {
      ncnt_g[n0 + idx] = c;
      d_inv[n0 + idx] = 1.0f / sqrtf((float)c);  // deg >= 1 (self-loop)
      s += (c + 7) & ~7;
    }
  }
  sd[tid] = s;
  __syncthreads();
  for (int o = 128; o > 0; o >>= 1) {
    if (tid < o) sd[tid] += sd[tid + o];
    __syncthreads();
  }
  if (tid == 0) btot[b] = sd[0];
}

// Level 2b: exclusive scan over bucket totals
__global__ void k_csr_base(const int* __restrict__ btot, int* __restrict__ bbase,
                           int* __restrict__ row_ptr) {
  __shared__ int sd[256];
  int t = threadIdx.x;
  int v = (t < NBUCK) ? btot[t] : 0;
  sd[t] = v;
  __syncthreads();
  for (int o = 1; o < 256; o <<= 1) {
    int x = (t >= o) ? sd[t - o] : 0;
    __syncthreads();
    sd[t] += x;
    __syncthreads();
  }
  if (t < NBUCK) bbase[t] = sd[t] - v;
  if (t == NBUCK - 1) row_ptr[NT] = sd[t];
}

// Level 2c: per-bucket LDS scan -> row_ptr; LDS cursors -> exact slots; write (t,g)
__global__ __launch_bounds__(256) void k_csr_fill(const uint2* __restrict__ part,
                                                  const int* __restrict__ gcur,
                                                  const int* __restrict__ ncnt_g,
                                                  const int* __restrict__ bbase,
                                                  const int* __restrict__ t_list,
                                                  const float* __restrict__ d_inv,
                                                  int* __restrict__ row_ptr,
                                                  uint2* __restrict__ edges) {
  __shared__ int sd[256];
  __shared__ int curs[1024];
  int b = blockIdx.x, tid = threadIdx.x;
  int n0 = b << 10;
  int nn = NT - n0; if (nn > 1024) nn = 1024;
  int base = bbase[b];
  int c[4], p[4];
  int s = 0;
#pragma unroll
  for (int j = 0; j < 4; j++) {
    int idx = tid * 4 + j;
    c[j] = (idx < nn) ? ncnt_g[n0 + idx] : 0;
    p[j] = (c[j] + 7) & ~7;
    s += p[j];
  }
  sd[tid] = s;
  __syncthreads();
  for (int o = 1; o < 256; o <<= 1) {
    int x = (tid >= o) ? sd[tid - o] : 0;
    __syncthreads();
    sd[tid] += x;
    __syncthreads();
  }
  int run = base + sd[tid] - s;
#pragma unroll
  for (int j = 0; j < 4; j++) {
    int idx = tid * 4 + j;
    if (idx < nn) { row_ptr[n0 + idx] = run; curs[idx] = run; }
    run += p[j];
  }
  __syncthreads();
  int m = gcur[b];
  const uint2* pp = part + (size_t)b * BCAP;
  for (int i = tid; i < m; i += 256) {
    uint2 pe = pp[i];
    int slot = atomicAdd(&curs[pe.x & 1023], 1);
    int t = t_list[pe.y];
    float g = d_inv[pe.x] * d_inv[t];
    uint2 v; v.x = (unsigned)t; v.y = __float_as_uint(g);
    edges[slot] = v;
  }
}

// ---------------- propagation ----------------
__global__ void k_init(const float4* __restrict__ ue, const float4* __restrict__ ie,
                       float4* __restrict__ cur, float4* __restrict__ acc, int nU4, int nTot4) {
  int i = blockIdx.x * 256 + threadIdx.x;
  if (i >= nTot4) return;
  float4 v = (i < nU4) ? ue[i] : ie[i - nU4];
  cur[i] = v;
  acc[i] = v;
}

// wave per node; edge lists padded to x8 with (idx=0,g=0) -> fully branchless.
__global__ __launch_bounds__(256) void k_agg(const int* __restrict__ row_ptr,
                                             const uint2* __restrict__ edges,
                                             const float* __restrict__ cur,
                                             float* __restrict__ nxt,
                                             float* __restrict__ acc) {
  int node = (blockIdx.x << 2) + (threadIdx.x >> 6);
  unsigned lane = threadIdx.x & 63;
  int s = row_ptr[node], e = row_ptr[node + 1];
  float sum = 0.f;
  for (int i = s; i < e; i += 8) {
    const uint4* e4 = (const uint4*)(edges + i);
    uint4 A = e4[0], B = e4[1], C = e4[2], D = e4[3];
    float c0 = cur[(A.x << 6) + lane];
    float c1 = cur[(A.z << 6) + lane];
    float c2 = cur[(B.x << 6) + lane];
    float c3 = cur[(B.z << 6) + lane];
    float c4 = cur[(C.x << 6) + lane];
    float c5 = cur[(C.z << 6) + lane];
    float c6 = cur[(D.x << 6) + lane];
    float c7 = cur[(D.z << 6) + lane];
    sum = fmaf(__uint_as_float(A.y), c0, sum);
    sum = fmaf(__uint_as_float(A.w), c1, sum);
    sum = fmaf(__uint_as_float(B.y), c2, sum);
    sum = fmaf(__uint_as_float(B.w), c3, sum);
    sum = fmaf(__uint_as_float(C.y), c4, sum);
    sum = fmaf(__uint_as_float(C.w), c5, sum);
    sum = fmaf(__uint_as_float(D.y), c6, sum);
    sum = fmaf(__uint_as_float(D.w), c7, sum);
  }
  unsigned o = ((unsigned)node << 6) + lane;
  nxt[o] = sum;
  acc[o] += sum;
}

// ---------------- losses ----------------
__global__ __launch_bounds__(256) void k_kl(const float* __restrict__ acc,
                                            const float* __restrict__ lin_w,
                                            const float* __restrict__ lin_b,
                                            double* __restrict__ accums) {
  __shared__ float lw[64 * 33];
  __shared__ float lb[64];
  for (int i = threadIdx.x; i < 64 * 32; i += 256) lw[(i >> 5) * 33 + (i & 31)] = lin_w[i];
  if (threadIdx.x < 64) lb[threadIdx.x] = lin_b[threadIdx.x];
  __syncthreads();
  int lane = threadIdx.x & 63;
  int w = (blockIdx.x * 256 + threadIdx.x) >> 6;
  int nw = (gridDim.x * 256) >> 6;
  double dsum = 0.0;
  for (int row = w; row < NT; row += nw) {
    float m = acc[row * 64 + lane];
    float sp = softplusf(m);
    float sd = lb[lane] + 1e-8f;
#pragma unroll
    for (int j = 0; j < 32; j++) sd = fmaf(__shfl(sp, j, 64), lw[lane * 33 + j], sd);
    float e2 = expf(2.f * sd);
    float kl = -0.5f * (1.f + 2.f * sd - m * m - e2);
    if (!isfinite(kl)) kl = 0.f;
    float rs = wsum(kl);
    if (lane == 0) dsum += (double)rs;
  }
  if (lane == 0) atomicAdd(&accums[1], dsum);
}

__global__ __launch_bounds__(256) void k_batch_user(
    const float* __restrict__ acc, const float* __restrict__ user_emb,
    const float* __restrict__ eps, const float* __restrict__ intent,
    const float* __restrict__ lin_w, const float* __restrict__ lin_b,
    const int* __restrict__ users, const int* __restrict__ pos_items,
    const int* __restrict__ neg_items,
    float* __restrict__ gen_o, float* __restrict__ int_o,
    unsigned short* __restrict__ gen_b, unsigned short* __restrict__ int_b,
    double* __restrict__ accums) {
  __shared__ float ui[64 * 130];
  __shared__ float lw[64 * 33];
  __shared__ float lb[64];
  __shared__ double red[8];
  for (int i = threadIdx.x; i < 64 * 128; i += 256) ui[(i >> 7) * 130 + (i & 127)] = intent[i];
  for (int i = threadIdx.x; i < 64 * 32; i += 256) lw[(i >> 5) * 33 + (i & 31)] = lin_w[i];
  if (threadIdx.x < 64) lb[threadIdx.x] = lin_b[threadIdx.x];
  __syncthreads();
  int lane = threadIdx.x & 63;
  int wid = threadIdx.x >> 6;
  int b = (blockIdx.x << 2) + wid;
  int u = users[b];
  float m = acc[u * 64 + lane];
  int k0 = lane * 2;
  float l0 = 0.f, l1 = 0.f;
  for (int d = 0; d < 64; d++) {
    float md = __shfl(m, d, 64);
    l0 = fmaf(md, ui[d * 130 + k0], l0);
    l1 = fmaf(md, ui[d * 130 + k0 + 1], l1);
  }
  float mx = wmax(fmaxf(l0, l1));
  float p0 = expf(l0 - mx), p1 = expf(l1 - mx);
  float tot = wsum(p0 + p1);
  p0 /= tot; p1 /= tot;
  float s = 0.f;
  for (int k = 0; k < 128; k++) {
    float pk = __shfl((k & 1) ? p1 : p0, k >> 1, 64);
    s = fmaf(pk, ui[lane * 130 + k], s);
  }
  float nrm = sqrtf(wsum(s * s));
  float io = s / nrm;
  int_o[b * 64 + lane] = io;
  int_b[b * 64 + lane] = f2b(io);
  float sp = softplusf(m);
  float sd = lb[lane] + 1e-8f;
#pragma unroll
  for (int j = 0; j < 32; j++) sd = fmaf(__shfl(sp, j, 64), lw[lane * 33 + j], sd);
  float ge = m + eps[u * 64 + lane] * sd;
  float gn = sqrtf(wsum(ge * ge));
  float go = ge / gn;
  gen_o[b * 64 + lane] = go;
  gen_b[b * 64 + lane] = f2b(go);
  int pi = pos_items[b], ni = neg_items[b];
  float pv = acc[(NU + pi) * 64 + lane];
  float nv = acc[(NU + ni) * 64 + lane];
  float ps = wsum(m * pv);
  float ns = wsum(m * nv);
  float bpr = softplusf(ns - ps);
  float ue = user_emb[u * 64 + lane];
  float es = wsum(ue * ue);
  if (lane == 0) { red[wid] = (double)bpr; red[4 + wid] = (double)es; }
  __syncthreads();
  if (threadIdx.x == 0) {
    atomicAdd(&accums[0], red[0] + red[1] + red[2] + red[3]);
    atomicAdd(&accums[2], red[4] + red[5] + red[6] + red[7]);
  }
}

__global__ __launch_bounds__(256) void k_batch_item(
    const float* __restrict__ acc, const float* __restrict__ item_emb,
    const float* __restrict__ eps, const float* __restrict__ intent,
    const float* __restrict__ lin_w, const float* __restrict__ lin_b,
    const int* __restrict__ pos_items, const int* __restrict__ neg_items,
    float* __restrict__ gen_o, float* __restrict__ int_o,
    unsigned short* __restrict__ gen_b, unsigned short* __restrict__ int_b,
    double* __restrict__ accums) {
  __shared__ float ui[64 * 130];
  __shared__ float lw[64 * 33];
  __shared__ float lb[64];
  __shared__ double red[4];
  for (int i = threadIdx.x; i < 64 * 128; i += 256) ui[(i >> 7) * 130 + (i & 127)] = intent[i];
  for (int i = threadIdx.x; i < 64 * 32; i += 256) lw[(i >> 5) * 33 + (i & 31)] = lin_w[i];
  if (threadIdx.x < 64) lb[threadIdx.x] = lin_b[threadIdx.x];
  __syncthreads();
  int lane = threadIdx.x & 63;
  int wid = threadIdx.x >> 6;
  int b = (blockIdx.x << 2) + wid;
  int pi = pos_items[b], ni = neg_items[b];
  int row = NU + pi;
  float m = acc[row * 64 + lane];
  int k0 = lane * 2;
  float l0 = 0.f, l1 = 0.f;
  for (int d = 0; d < 64; d++) {
    float md = __shfl(m, d, 64);
    l0 = fmaf(md, ui[d * 130 + k0], l0);
    l1 = fmaf(md, ui[d * 130 + k0 + 1], l1);
  }
  float mx = wmax(fmaxf(l0, l1));
  float p0 = expf(l0 - mx), p1 = expf(l1 - mx);
  float tot = wsum(p0 + p1);
  p0 /= tot; p1 /= tot;
  float s = 0.f;
  for (int k = 0; k < 128; k++) {
    float pk = __shfl((k & 1) ? p1 : p0, k >> 1, 64);
    s = fmaf(pk, ui[lane * 130 + k], s);
  }
  float nrm = sqrtf(wsum(s * s));
  float io = s / nrm;
  int_o[b * 64 + lane] = io;
  int_b[b * 64 + lane] = f2b(io);
  float sp = softplusf(m);
  float sd = lb[lane] + 1e-8f;
#pragma unroll
  for (int j = 0; j < 32; j++) sd = fmaf(__shfl(sp, j, 64), lw[lane * 33 + j], sd);
  float ge = m + eps[row * 64 + lane] * sd;
  float gn = sqrtf(wsum(ge * ge));
  float go = ge / gn;
  gen_o[b * 64 + lane] = go;
  gen_b[b * 64 + lane] = f2b(go);
  float a0 = item_emb[pi * 64 + lane];
  float a1 = item_emb[ni * 64 + lane];
  float es = wsum(a0 * a0 + a1 * a1);
  if (lane == 0) red[wid] = (double)es;
  __syncthreads();
  if (threadIdx.x == 0) atomicAdd(&accums[2], red[0] + red[1] + red[2] + red[3]);
}

__global__ void k_int(const float* __restrict__ ui, const float* __restrict__ ii,
                      double* __restrict__ accums) {
  float s = 0.f;
  for (int i = threadIdx.x; i < 64 * 128; i += 256) {
    float a = ui[i], b = ii[i];
    s = fmaf(a, a, s);
    s = fmaf(b, b, s);
  }
  s = wsum(s);
  __shared__ float red[4];
  if ((threadIdx.x & 63) == 0) red[threadIdx.x >> 6] = s;
  __syncthreads();
  if (threadIdx.x == 0) atomicAdd(&accums[3], (double)(red[0] + red[1] + red[2] + red[3]));
}

// ---------------- InfoNCE negatives via bf16 MFMA ----------------
// S = e1 . e2^T (4096x4096x64), nsum_i += exp(5*S[i][j]); per-wave 16x16 tile.
// blockIdx.y = pair*4 + jq (j quarter); block = 4 waves = 4 i-tiles (64 rows).
__global__ __launch_bounds__(256) void k_nce_mfma(
    const unsigned short* __restrict__ e1u, const unsigned short* __restrict__ e2u,
    const unsigned short* __restrict__ e1i, const unsigned short* __restrict__ e2i,
    float* __restrict__ negu, float* __restrict__ negi) {
  int pair = blockIdx.y >> 2, jq = blockIdx.y & 3;
  const unsigned short* e1 = pair ? e1i : e1u;
  const unsigned short* e2 = pair ? e2i : e2u;
  float* nego = pair ? negi : negu;
  int wid = threadIdx.x >> 6, lane = threadIdx.x & 63;
  int q = lane >> 4, n = lane & 15;
  int i0 = blockIdx.x * 64 + wid * 16;
  const bf16x8* arow = (const bf16x8*)(e1 + (size_t)(i0 + n) * 64 + q * 8);
  bf16x8 a0 = arow[0];  // A[m=n][k=q*8..q*8+7]
  bf16x8 a1 = arow[4];  // k += 32
  f32x4 accv = {0.f, 0.f, 0.f, 0.f};
  int j0 = jq * 1024;
  for (int jt = 0; jt < 64; jt++) {
    const bf16x8* brow = (const bf16x8*)(e2 + (size_t)(j0 + jt * 16 + n) * 64 + q * 8);
    bf16x8 b0 = brow[0];
    bf16x8 b1 = brow[4];
    f32x4 c = {0.f, 0.f, 0.f, 0.f};
    c = __builtin_amdgcn_mfma_f32_16x16x32_bf16(a0, b0, c, 0, 0, 0);
    c = __builtin_amdgcn_mfma_f32_16x16x32_bf16(a1, b1, c, 0, 0, 0);
#pragma unroll
    for (int r = 0; r < 4; r++) accv[r] += __expf(5.0f * c[r]);
  }
  // C layout: col=lane&15, row=q*4+r. Reduce over the 16 cols (lanes of quad).
#pragma unroll
  for (int o = 1; o < 16; o <<= 1) {
#pragma unroll
    for (int r = 0; r < 4; r++) accv[r] += __shfl_xor(accv[r], o, 64);
  }
  if (n == 0) {
#pragma unroll
    for (int r = 0; r < 4; r++) atomicAdd(&nego[i0 + q * 4 + r], accv[r]);
  }
}

__global__ __launch_bounds__(256) void k_nce_final(
    const float* __restrict__ ugen, const float* __restrict__ uio,
    const float* __restrict__ igen, const float* __restrict__ iio,
    const float* __restrict__ negu, const float* __restrict__ negi,
    double* __restrict__ accums) {
  __shared__ double red[4];
  int lane = threadIdx.x & 63, wid = threadIdx.x >> 6;
  int w = blockIdx.x * 4 + wid;
  int pair = w >> 12, i = w & 4095;
  const float* e1 = pair ? igen : ugen;
  const float* e2 = pair ? iio : uio;
  const float* ng = pair ? negi : negu;
  float dot = wsum(e1[i * 64 + lane] * e2[i * 64 + lane]);
  if (lane == 0) {
    float pos = expf(dot * 5.f);
    red[wid] = (double)(-logf(pos / (ng[i] + 1e-8f) + 1e-8f));
  }
  __syncthreads();
  if (threadIdx.x == 0) atomicAdd(&accums[4], red[0] + red[1] + red[2] + red[3]);
}

__global__ void k_fin(const double* __restrict__ accums, float* __restrict__ out) {
  if (threadIdx.x == 0 && blockIdx.x == 0) {
    double bpr = accums[0] / (double)BB;
    double kl = 0.01 * accums[1] / (double)NT;
    out[0] = (float)(bpr + kl);
    out[1] = (float)(0.1 * accums[4] / (double)BB);
    out[2] = (float)(1e-5 * accums[2]);
    out[3] = (float)(1e-5 * accums[3]);
  }
}

extern "C" void kernel_launch(void* const* d_in, const int* in_sizes, int n_in,
                              void* d_out, int out_size, void* d_ws, size_t ws_size,
                              hipStream_t stream) {
  const float* user_emb = (const float*)d_in[0];
  const float* item_emb = (const float*)d_in[1];
  const float* user_int = (const float*)d_in[2];
  const float* item_int = (const float*)d_in[3];
  const float* lin_w = (const float*)d_in[4];
  const float* lin_b = (const float*)d_in[5];
  const float* eps = (const float*)d_in[6];
  const int* h_list = (const int*)d_in[7];
  const int* t_list = (const int*)d_in[8];
  const int* users = (const int*)d_in[9];
  const int* pos_items = (const int*)d_in[10];
  const int* neg_items = (const int*)d_in[11];
  float* out = (float*)d_out;
  const int E = in_sizes[7];
  const size_t Ecap = (size_t)E + 8 * (size_t)NT;  // padded-edge capacity

  char* ws = (char*)d_ws;
  size_t off = 0;
  auto take = [&](size_t bytes) -> char* {
    char* p = ws + off;
    off = (off + bytes + 255) & ~(size_t)255;
    return p;
  };
  int* row_ptr = (int*)take((size_t)(NT + 1) * 4);
  float* d_inv = (float*)take((size_t)NT * 4);
  int* ncnt_g = (int*)take((size_t)NT * 4);
  int* gcur = (int*)take(NBUCK * 4);
  int* btot = (int*)take(NBUCK * 4);
  int* bbase = (int*)take(NBUCK * 4);
  uint2* edges = (uint2*)take(Ecap * 8);
  float* bufA = (float*)take((size_t)NT * 64 * 4);
  float* bufB = (float*)take((size_t)NT * 64 * 4);
  float* acc = (float*)take((size_t)NT * 64 * 4);
  float* ugen = (float*)take((size_t)BB * 64 * 4);
  float* igen = (float*)take((size_t)BB * 64 * 4);
  float* uio = (float*)take((size_t)BB * 64 * 4);
  float* iio = (float*)take((size_t)BB * 64 * 4);
  unsigned short* ugen_b = (unsigned short*)take((size_t)BB * 64 * 2);
  unsigned short* igen_b = (unsigned short*)take((size_t)BB * 64 * 2);
  unsigned short* uio_b = (unsigned short*)take((size_t)BB * 64 * 2);
  unsigned short* iio_b = (unsigned short*)take((size_t)BB * 64 * 2);
  float* negu = (float*)take((size_t)BB * 4);
  float* negi = (float*)take((size_t)BB * 4);
  double* accums = (double*)take(64);
  if (off > ws_size) return;
  // part[] (NBUCK*BCAP uint2 = 28.9MB) aliases bufB (38.4MB): bufB is first
  // written by k_agg#1, after k_csr_fill's last read of part.
  uint2* part = (uint2*)bufB;

  hipMemsetAsync(gcur, 0, NBUCK * 4, stream);
  hipMemsetAsync(edges, 0, Ecap * 8, stream);  // pad entries: idx 0, g = 0
  hipMemsetAsync(negu, 0, (size_t)BB * 4, stream);
  hipMemsetAsync(negi, 0, (size_t)BB * 4, stream);
  hipMemsetAsync(accums, 0, 64, stream);

  int gridP = (E + 4095) / 4096;
  k_part<<<gridP, 256, 0, stream>>>(h_list, gcur, part, E);
  k_csr_count<<<NBUCK, 256, 0, stream>>>(part, gcur, ncnt_g, d_inv, btot);
  k_csr_base<<<1, 256, 0, stream>>>(btot, bbase, row_ptr);
  k_csr_fill<<<NBUCK, 256, 0, stream>>>(part, gcur, ncnt_g, bbase, t_list, d_inv,
                                        row_ptr, edges);

  int nU4 = NU * 16, nTot4 = NT * 16;
  k_init<<<(nTot4 + 255) / 256, 256, 0, stream>>>((const float4*)user_emb, (const float4*)item_emb,
                                                  (float4*)bufA, (float4*)acc, nU4, nTot4);
  int gridAgg = NT / 4;
  k_agg<<<gridAgg, 256, 0, stream>>>(row_ptr, edges, bufA, bufB, acc);
  k_agg<<<gridAgg, 256, 0, stream>>>(row_ptr, edges, bufB, bufA, acc);
  k_agg<<<gridAgg, 256, 0, stream>>>(row_ptr, edges, bufA, bufB, acc);

  k_kl<<<512, 256, 0, stream>>>(acc, lin_w, lin_b, accums);
  k_batch_user<<<BB / 4, 256, 0, stream>>>(acc, user_emb, eps, user_int, lin_w, lin_b,
                                           users, pos_items, neg_items,
                                           ugen, uio, ugen_b, uio_b, accums);
  k_batch_item<<<BB / 4, 256, 0, stream>>>(acc, item_emb, eps, item_int, lin_w, lin_b,
                                           pos_items, neg_items,
                                           igen, iio, igen_b, iio_b, accums);
  k_int<<<1, 256, 0, stream>>>(user_int, item_int, accums);
  k_nce_mfma<<<dim3(64, 8), 256, 0, stream>>>(ugen_b, uio_b, igen_b, iio_b, negu, negi);
  k_nce_final<<<(2 * BB) / 4, 256, 0, stream>>>(ugen, uio, igen, iio, negu, negi, accums);
  k_fin<<<1, 64, 0, stream>>>(accums, out);
}

// Round 5
// 845.131 us; speedup vs baseline: 1.6186x; 1.0989x over previous
//
#include <hip/hip_runtime.h>

#define NU 50000
#define NI 100000
#define NT 150000
#define BB 4096
#define NBUCK 147   // ceil(NT/1024)
#define BCAP 24576  // per-bucket edge capacity: mean 21504, sd ~143 -> +21 sigma
#define NCH 8       // chunks per bucket in CSR build

typedef __attribute__((ext_vector_type(8))) short bf16x8;
typedef __attribute__((ext_vector_type(4))) float f32x4;

__device__ __forceinline__ float softplusf(float x) {
  return fmaxf(x, 0.f) + log1pf(expf(-fabsf(x)));
}
__device__ __forceinline__ float wsum(float v) {
#pragma unroll
  for (int o = 32; o > 0; o >>= 1) v += __shfl_xor(v, o, 64);
  return v;
}
__device__ __forceinline__ float wmax(float v) {
#pragma unroll
  for (int o = 32; o > 0; o >>= 1) v = fmaxf(v, __shfl_xor(v, o, 64));
  return v;
}
__device__ __forceinline__ unsigned short f2b(float x) {
  unsigned u = __float_as_uint(x);
  return (unsigned short)((u + 0x7FFFu + ((u >> 16) & 1u)) >> 16);
}

// ---------------- CSR build ----------------
// Level 1: partition edges into NBUCK coarse buckets (h >> 10); record (h, t).
__global__ __launch_bounds__(256) void k_part(const int* __restrict__ h,
                                              const int* __restrict__ t,
                                              int* __restrict__ gcur,
                                              uint2* __restrict__ part, int E) {
  __shared__ int cnt[NBUCK];
  __shared__ int base[NBUCK];
  for (int b = threadIdx.x; b < NBUCK; b += 256) cnt[b] = 0;
  __syncthreads();
  int e0 = blockIdx.x * 4096 + threadIdx.x * 16;
  int nval = E - e0;
  nval = nval < 0 ? 0 : (nval > 16 ? 16 : nval);
  int hh[16], tt[16];
  if (nval == 16) {
    const int4* hp = (const int4*)(h + e0);
    const int4* tp = (const int4*)(t + e0);
#pragma unroll
    for (int j = 0; j < 4; j++) {
      int4 v = hp[j];
      hh[j * 4] = v.x; hh[j * 4 + 1] = v.y; hh[j * 4 + 2] = v.z; hh[j * 4 + 3] = v.w;
      int4 w = tp[j];
      tt[j * 4] = w.x; tt[j * 4 + 1] = w.y; tt[j * 4 + 2] = w.z; tt[j * 4 + 3] = w.w;
    }
  } else {
    for (int j = 0; j < nval; j++) { hh[j] = h[e0 + j]; tt[j] = t[e0 + j]; }
  }
  for (int j = 0; j < nval; j++) atomicAdd(&cnt[hh[j] >> 10], 1);
  __syncthreads();
  for (int b = threadIdx.x; b < NBUCK; b += 256) {
    int c = cnt[b];
    base[b] = c ? atomicAdd(&gcur[b], c) : 0;
    cnt[b] = 0;
  }
  __syncthreads();
  for (int j = 0; j < nval; j++) {
    int b = hh[j] >> 10;
    int r = atomicAdd(&cnt[b], 1);
    uint2 v; v.x = (unsigned)hh[j]; v.y = (unsigned)tt[j];
    part[(size_t)b * BCAP + base[b] + r] = v;
  }
}

// Level 2a: per-(bucket,chunk) node histogram -> cnt_chunk[b][c][1024]
__global__ __launch_bounds__(256) void k_count2(const uint2* __restrict__ part,
                                                const int* __restrict__ gcur,
                                                int* __restrict__ cnt_chunk) {
  __shared__ int hist[1024];
  int b = blockIdx.x, c = blockIdx.y, tid = threadIdx.x;
  for (int i = tid; i < 1024; i += 256) hist[i] = 0;
  __syncthreads();
  int m = gcur[b];
  int lo = (int)(((long long)m * c) >> 3);
  int hi = (int)(((long long)m * (c + 1)) >> 3);
  const uint2* pp = part + (size_t)b * BCAP;
  for (int i = lo + tid; i < hi; i += 256) atomicAdd(&hist[pp[i].x & 1023], 1);
  __syncthreads();
  int* dst = cnt_chunk + (((size_t)b * NCH + c) << 10);
  for (int i = tid; i < 1024; i += 256) dst[i] = hist[i];
}

// Level 2b: per bucket -- chunk prefixes (in place), deg -> d_inv,
// in-bucket exclusive prefix of 16-padded degs -> rloc, bucket total -> btot
__global__ __launch_bounds__(256) void k_node(int* __restrict__ cnt_chunk,
                                              int* __restrict__ rloc_g,
                                              float* __restrict__ d_inv,
                                              int* __restrict__ btot) {
  __shared__ int sd[256];
  int b = blockIdx.x, tid = threadIdx.x;
  int n0 = b << 10;
  int pd[4];
  int s = 0;
#pragma unroll
  for (int j = 0; j < 4; j++) {
    int idx = tid * 4 + j;
    int run = 0;
#pragma unroll
    for (int c = 0; c < NCH; c++) {
      size_t a = (((size_t)b * NCH + c) << 10) + idx;
      int v = cnt_chunk[a];
      cnt_chunk[a] = run;
      run += v;
    }
    int n = n0 + idx;
    if (n < NT) {
      d_inv[n] = 1.0f / sqrtf((float)run);  // deg >= 1 (self-loop)
      pd[j] = (run + 15) & ~15;
    } else pd[j] = 0;
    s += pd[j];
  }
  sd[tid] = s;
  __syncthreads();
  for (int o = 1; o < 256; o <<= 1) {
    int x = (tid >= o) ? sd[tid - o] : 0;
    __syncthreads();
    sd[tid] += x;
    __syncthreads();
  }
  int run2 = sd[tid] - s;
#pragma unroll
  for (int j = 0; j < 4; j++) {
    int idx = tid * 4 + j, n = n0 + idx;
    if (n < NT) rloc_g[n] = run2;
    run2 += pd[j];
  }
  if (tid == 255) btot[b] = sd[255];
}

// Level 2c: exclusive scan over bucket totals
__global__ void k_csr_base(const int* __restrict__ btot, int* __restrict__ bbase,
                           int* __restrict__ row_ptr) {
  __shared__ int sd[256];
  int t = threadIdx.x;
  int v = (t < NBUCK) ? btot[t] : 0;
  sd[t] = v;
  __syncthreads();
  for (int o = 1; o < 256; o <<= 1) {
    int x = (t >= o) ? sd[t - o] : 0;
    __syncthreads();
    sd[t] += x;
    __syncthreads();
  }
  if (t < NBUCK) bbase[t] = sd[t] - v;
  if (t == NBUCK - 1) row_ptr[NT] = sd[t];
}

__global__ void k_rowptr(const int* __restrict__ bbase, const int* __restrict__ rloc_g,
                         int* __restrict__ row_ptr) {
  int n = blockIdx.x * 256 + threadIdx.x;
  if (n < NT) row_ptr[n] = bbase[n >> 10] + rloc_g[n];
}

// Level 2d: per-(bucket,chunk) fill; LDS cursors seeded at row_ptr + chunk prefix
__global__ __launch_bounds__(256) void k_fill2(const uint2* __restrict__ part,
                                               const int* __restrict__ gcur,
                                               const int* __restrict__ chunkpre,
                                               const int* __restrict__ row_ptr,
                                               const float* __restrict__ d_inv,
                                               uint2* __restrict__ edges) {
  __shared__ int curs[1024];
  __shared__ float dl[1024];
  int b = blockIdx.x, c = blockIdx.y, tid = threadIdx.x;
  int n0 = b << 10;
  const int* pre = chunkpre + (((size_t)b * NCH + c) << 10);
  for (int i = tid; i < 1024; i += 256) {
    int n = n0 + i;
    if (n < NT) {
      curs[i] = row_ptr[n] + pre[i];
      dl[i] = d_inv[n];
    }
  }
  __syncthreads();
  int m = gcur[b];
  int lo = (int)(((long long)m * c) >> 3);
  int hi = (int)(((long long)m * (c + 1)) >> 3);
  const uint2* pp = part + (size_t)b * BCAP;
  for (int i = lo + tid; i < hi; i += 256) {
    uint2 pe = pp[i];
    int slot = atomicAdd(&curs[pe.x & 1023], 1);
    float g = dl[pe.x & 1023] * d_inv[pe.y];
    uint2 v; v.x = pe.y; v.y = __float_as_uint(g);
    edges[slot] = v;
  }
}

// ---------------- propagation ----------------
__global__ void k_init(const float4* __restrict__ ue, const float4* __restrict__ ie,
                       float4* __restrict__ cur, float4* __restrict__ acc, int nU4, int nTot4) {
  int i = blockIdx.x * 256 + threadIdx.x;
  if (i >= nTot4) return;
  float4 v = (i < nU4) ? ue[i] : ie[i - nU4];
  cur[i] = v;
  acc[i] = v;
}

// wave per node; edge lists padded to x16 with (idx=0,g=0) -> branchless,
// 16 coalesced row-gathers in flight per wave.
__global__ __launch_bounds__(256) void k_agg(const int* __restrict__ row_ptr,
                                             const uint2* __restrict__ edges,
                                             const float* __restrict__ cur,
                                             float* __restrict__ nxt,
                                             float* __restrict__ acc) {
  int node = (blockIdx.x << 2) + (threadIdx.x >> 6);
  unsigned lane = threadIdx.x & 63;
  int s = row_ptr[node], e = row_ptr[node + 1];
  float sum = 0.f;
  for (int i = s; i < e; i += 16) {
    const uint4* e4 = (const uint4*)(edges + i);
    uint4 A = e4[0], B = e4[1], C = e4[2], D = e4[3];
    uint4 F = e4[4], G = e4[5], H = e4[6], I = e4[7];
    float c0 = cur[(A.x << 6) + lane];
    float c1 = cur[(A.z << 6) + lane];
    float c2 = cur[(B.x << 6) + lane];
    float c3 = cur[(B.z << 6) + lane];
    float c4 = cur[(C.x << 6) + lane];
    float c5 = cur[(C.z << 6) + lane];
    float c6 = cur[(D.x << 6) + lane];
    float c7 = cur[(D.z << 6) + lane];
    float c8 = cur[(F.x << 6) + lane];
    float c9 = cur[(F.z << 6) + lane];
    float ca = cur[(G.x << 6) + lane];
    float cb = cur[(G.z << 6) + lane];
    float cc = cur[(H.x << 6) + lane];
    float cd = cur[(H.z << 6) + lane];
    float ce = cur[(I.x << 6) + lane];
    float cf = cur[(I.z << 6) + lane];
    sum = fmaf(__uint_as_float(A.y), c0, sum);
    sum = fmaf(__uint_as_float(A.w), c1, sum);
    sum = fmaf(__uint_as_float(B.y), c2, sum);
    sum = fmaf(__uint_as_float(B.w), c3, sum);
    sum = fmaf(__uint_as_float(C.y), c4, sum);
    sum = fmaf(__uint_as_float(C.w), c5, sum);
    sum = fmaf(__uint_as_float(D.y), c6, sum);
    sum = fmaf(__uint_as_float(D.w), c7, sum);
    sum = fmaf(__uint_as_float(F.y), c8, sum);
    sum = fmaf(__uint_as_float(F.w), c9, sum);
    sum = fmaf(__uint_as_float(G.y), ca, sum);
    sum = fmaf(__uint_as_float(G.w), cb, sum);
    sum = fmaf(__uint_as_float(H.y), cc, sum);
    sum = fmaf(__uint_as_float(H.w), cd, sum);
    sum = fmaf(__uint_as_float(I.y), ce, sum);
    sum = fmaf(__uint_as_float(I.w), cf, sum);
  }
  unsigned o = ((unsigned)node << 6) + lane;
  nxt[o] = sum;
  acc[o] += sum;
}

// ---------------- losses ----------------
__global__ __launch_bounds__(256) void k_kl(const float* __restrict__ acc,
                                            const float* __restrict__ lin_w,
                                            const float* __restrict__ lin_b,
                                            double* __restrict__ accums) {
  __shared__ float lw[64 * 33];
  __shared__ float lb[64];
  for (int i = threadIdx.x; i < 64 * 32; i += 256) lw[(i >> 5) * 33 + (i & 31)] = lin_w[i];
  if (threadIdx.x < 64) lb[threadIdx.x] = lin_b[threadIdx.x];
  __syncthreads();
  int lane = threadIdx.x & 63;
  int w = (blockIdx.x * 256 + threadIdx.x) >> 6;
  int nw = (gridDim.x * 256) >> 6;
  double dsum = 0.0;
  for (int row = w; row < NT; row += nw) {
    float m = acc[row * 64 + lane];
    float sp = softplusf(m);
    float sd = lb[lane] + 1e-8f;
#pragma unroll
    for (int j = 0; j < 32; j++) sd = fmaf(__shfl(sp, j, 64), lw[lane * 33 + j], sd);
    float e2 = expf(2.f * sd);
    float kl = -0.5f * (1.f + 2.f * sd - m * m - e2);
    if (!isfinite(kl)) kl = 0.f;
    float rs = wsum(kl);
    if (lane == 0) dsum += (double)rs;
  }
  if (lane == 0) atomicAdd(&accums[1], dsum);
}

__global__ __launch_bounds__(256) void k_batch_user(
    const float* __restrict__ acc, const float* __restrict__ user_emb,
    const float* __restrict__ eps, const float* __restrict__ intent,
    const float* __restrict__ lin_w, const float* __restrict__ lin_b,
    const int* __restrict__ users, const int* __restrict__ pos_items,
    const int* __restrict__ neg_items,
    float* __restrict__ gen_o, float* __restrict__ int_o,
    unsigned short* __restrict__ gen_b, unsigned short* __restrict__ int_b,
    double* __restrict__ accums) {
  __shared__ float ui[64 * 130];
  __shared__ float lw[64 * 33];
  __shared__ float lb[64];
  __shared__ double red[8];
  for (int i = threadIdx.x; i < 64 * 128; i += 256) ui[(i >> 7) * 130 + (i & 127)] = intent[i];
  for (int i = threadIdx.x; i < 64 * 32; i += 256) lw[(i >> 5) * 33 + (i & 31)] = lin_w[i];
  if (threadIdx.x < 64) lb[threadIdx.x] = lin_b[threadIdx.x];
  __syncthreads();
  int lane = threadIdx.x & 63;
  int wid = threadIdx.x >> 6;
  int b = (blockIdx.x << 2) + wid;
  int u = users[b];
  float m = acc[u * 64 + lane];
  int k0 = lane * 2;
  float l0 = 0.f, l1 = 0.f;
  for (int d = 0; d < 64; d++) {
    float md = __shfl(m, d, 64);
    l0 = fmaf(md, ui[d * 130 + k0], l0);
    l1 = fmaf(md, ui[d * 130 + k0 + 1], l1);
  }
  float mx = wmax(fmaxf(l0, l1));
  float p0 = expf(l0 - mx), p1 = expf(l1 - mx);
  float tot = wsum(p0 + p1);
  p0 /= tot; p1 /= tot;
  float s = 0.f;
  for (int k = 0; k < 128; k++) {
    float pk = __shfl((k & 1) ? p1 : p0, k >> 1, 64);
    s = fmaf(pk, ui[lane * 130 + k], s);
  }
  float nrm = sqrtf(wsum(s * s));
  float io = s / nrm;
  int_o[b * 64 + lane] = io;
  int_b[b * 64 + lane] = f2b(io);
  float sp = softplusf(m);
  float sd = lb[lane] + 1e-8f;
#pragma unroll
  for (int j = 0; j < 32; j++) sd = fmaf(__shfl(sp, j, 64), lw[lane * 33 + j], sd);
  float ge = m + eps[u * 64 + lane] * sd;
  float gn = sqrtf(wsum(ge * ge));
  float go = ge / gn;
  gen_o[b * 64 + lane] = go;
  gen_b[b * 64 + lane] = f2b(go);
  int pi = pos_items[b], ni = neg_items[b];
  float pv = acc[(NU + pi) * 64 + lane];
  float nv = acc[(NU + ni) * 64 + lane];
  float ps = wsum(m * pv);
  float ns = wsum(m * nv);
  float bpr = softplusf(ns - ps);
  float ue = user_emb[u * 64 + lane];
  float es = wsum(ue * ue);
  if (lane == 0) { red[wid] = (double)bpr; red[4 + wid] = (double)es; }
  __syncthreads();
  if (threadIdx.x == 0) {
    atomicAdd(&accums[0], red[0] + red[1] + red[2] + red[3]);
    atomicAdd(&accums[2], red[4] + red[5] + red[6] + red[7]);
  }
}

__global__ __launch_bounds__(256) void k_batch_item(
    const float* __restrict__ acc, const float* __restrict__ item_emb,
    const float* __restrict__ eps, const float* __restrict__ intent,
    const float* __restrict__ lin_w, const float* __restrict__ lin_b,
    const int* __restrict__ pos_items, const int* __restrict__ neg_items,
    float* __restrict__ gen_o, float* __restrict__ int_o,
    unsigned short* __restrict__ gen_b, unsigned short* __restrict__ int_b,
    double* __restrict__ accums) {
  __shared__ float ui[64 * 130];
  __shared__ float lw[64 * 33];
  __shared__ float lb[64];
  __shared__ double red[4];
  for (int i = threadIdx.x; i < 64 * 128; i += 256) ui[(i >> 7) * 130 + (i & 127)] = intent[i];
  for (int i = threadIdx.x; i < 64 * 32; i += 256) lw[(i >> 5) * 33 + (i & 31)] = lin_w[i];
  if (threadIdx.x < 64) lb[threadIdx.x] = lin_b[threadIdx.x];
  __syncthreads();
  int lane = threadIdx.x & 63;
  int wid = threadIdx.x >> 6;
  int b = (blockIdx.x << 2) + wid;
  int pi = pos_items[b], ni = neg_items[b];
  int row = NU + pi;
  float m = acc[row * 64 + lane];
  int k0 = lane * 2;
  float l0 = 0.f, l1 = 0.f;
  for (int d = 0; d < 64; d++) {
    float md = __shfl(m, d, 64);
    l0 = fmaf(md, ui[d * 130 + k0], l0);
    l1 = fmaf(md, ui[d * 130 + k0 + 1], l1);
  }
  float mx = wmax(fmaxf(l0, l1));
  float p0 = expf(l0 - mx), p1 = expf(l1 - mx);
  float tot = wsum(p0 + p1);
  p0 /= tot; p1 /= tot;
  float s = 0.f;
  for (int k = 0; k < 128; k++) {
    float pk = __shfl((k & 1) ? p1 : p0, k >> 1, 64);
    s = fmaf(pk, ui[lane * 130 + k], s);
  }
  float nrm = sqrtf(wsum(s * s));
  float io = s / nrm;
  int_o[b * 64 + lane] = io;
  int_b[b * 64 + lane] = f2b(io);
  float sp = softplusf(m);
  float sd = lb[lane] + 1e-8f;
#pragma unroll
  for (int j = 0; j < 32; j++) sd = fmaf(__shfl(sp, j, 64), lw[lane * 33 + j], sd);
  float ge = m + eps[row * 64 + lane] * sd;
  float gn = sqrtf(wsum(ge * ge));
  float go = ge / gn;
  gen_o[b * 64 + lane] = go;
  gen_b[b * 64 + lane] = f2b(go);
  float a0 = item_emb[pi * 64 + lane];
  float a1 = item_emb[ni * 64 + lane];
  float es = wsum(a0 * a0 + a1 * a1);
  if (lane == 0) red[wid] = (double)es;
  __syncthreads();
  if (threadIdx.x == 0) atomicAdd(&accums[2], red[0] + red[1] + red[2] + red[3]);
}

__global__ void k_int(const float* __restrict__ ui, const float* __restrict__ ii,
                      double* __restrict__ accums) {
  float s = 0.f;
  for (int i = threadIdx.x; i < 64 * 128; i += 256) {
    float a = ui[i], b = ii[i];
    s = fmaf(a, a, s);
    s = fmaf(b, b, s);
  }
  s = wsum(s);
  __shared__ float red[4];
  if ((threadIdx.x & 63) == 0) red[threadIdx.x >> 6] = s;
  __syncthreads();
  if (threadIdx.x == 0) atomicAdd(&accums[3], (double)(red[0] + red[1] + red[2] + red[3]));
}

// ---------------- InfoNCE negatives via bf16 MFMA ----------------
__global__ __launch_bounds__(256) void k_nce_mfma(
    const unsigned short* __restrict__ e1u, const unsigned short* __restrict__ e2u,
    const unsigned short* __restrict__ e1i, const unsigned short* __restrict__ e2i,
    float* __restrict__ negu, float* __restrict__ negi) {
  int pair = blockIdx.y >> 2, jq = blockIdx.y & 3;
  const unsigned short* e1 = pair ? e1i : e1u;
  const unsigned short* e2 = pair ? e2i : e2u;
  float* nego = pair ? negi : negu;
  int wid = threadIdx.x >> 6, lane = threadIdx.x & 63;
  int q = lane >> 4, n = lane & 15;
  int i0 = blockIdx.x * 64 + wid * 16;
  const bf16x8* arow = (const bf16x8*)(e1 + (size_t)(i0 + n) * 64 + q * 8);
  bf16x8 a0 = arow[0];
  bf16x8 a1 = arow[4];
  f32x4 accv = {0.f, 0.f, 0.f, 0.f};
  int j0 = jq * 1024;
  for (int jt = 0; jt < 64; jt++) {
    const bf16x8* brow = (const bf16x8*)(e2 + (size_t)(j0 + jt * 16 + n) * 64 + q * 8);
    bf16x8 b0 = brow[0];
    bf16x8 b1 = brow[4];
    f32x4 c = {0.f, 0.f, 0.f, 0.f};
    c = __builtin_amdgcn_mfma_f32_16x16x32_bf16(a0, b0, c, 0, 0, 0);
    c = __builtin_amdgcn_mfma_f32_16x16x32_bf16(a1, b1, c, 0, 0, 0);
#pragma unroll
    for (int r = 0; r < 4; r++) accv[r] += __expf(5.0f * c[r]);
  }
#pragma unroll
  for (int o = 1; o < 16; o <<= 1) {
#pragma unroll
    for (int r = 0; r < 4; r++) accv[r] += __shfl_xor(accv[r], o, 64);
  }
  if (n == 0) {
#pragma unroll
    for (int r = 0; r < 4; r++) atomicAdd(&nego[i0 + q * 4 + r], accv[r]);
  }
}

__global__ __launch_bounds__(256) void k_nce_final(
    const float* __restrict__ ugen, const float* __restrict__ uio,
    const float* __restrict__ igen, const float* __restrict__ iio,
    const float* __restrict__ negu, const float* __restrict__ negi,
    double* __restrict__ accums) {
  __shared__ double red[4];
  int lane = threadIdx.x & 63, wid = threadIdx.x >> 6;
  int w = blockIdx.x * 4 + wid;
  int pair = w >> 12, i = w & 4095;
  const float* e1 = pair ? igen : ugen;
  const float* e2 = pair ? iio : uio;
  const float* ng = pair ? negi : negu;
  float dot = wsum(e1[i * 64 + lane] * e2[i * 64 + lane]);
  if (lane == 0) {
    float pos = expf(dot * 5.f);
    red[wid] = (double)(-logf(pos / (ng[i] + 1e-8f) + 1e-8f));
  }
  __syncthreads();
  if (threadIdx.x == 0) atomicAdd(&accums[4], red[0] + red[1] + red[2] + red[3]);
}

__global__ void k_fin(const double* __restrict__ accums, float* __restrict__ out) {
  if (threadIdx.x == 0 && blockIdx.x == 0) {
    double bpr = accums[0] / (double)BB;
    double kl = 0.01 * accums[1] / (double)NT;
    out[0] = (float)(bpr + kl);
    out[1] = (float)(0.1 * accums[4] / (double)BB);
    out[2] = (float)(1e-5 * accums[2]);
    out[3] = (float)(1e-5 * accums[3]);
  }
}

extern "C" void kernel_launch(void* const* d_in, const int* in_sizes, int n_in,
                              void* d_out, int out_size, void* d_ws, size_t ws_size,
                              hipStream_t stream) {
  const float* user_emb = (const float*)d_in[0];
  const float* item_emb = (const float*)d_in[1];
  const float* user_int = (const float*)d_in[2];
  const float* item_int = (const float*)d_in[3];
  const float* lin_w = (const float*)d_in[4];
  const float* lin_b = (const float*)d_in[5];
  const float* eps = (const float*)d_in[6];
  const int* h_list = (const int*)d_in[7];
  const int* t_list = (const int*)d_in[8];
  const int* users = (const int*)d_in[9];
  const int* pos_items = (const int*)d_in[10];
  const int* neg_items = (const int*)d_in[11];
  float* out = (float*)d_out;
  const int E = in_sizes[7];
  const size_t Ecap = (size_t)E + 16 * (size_t)NT;  // x16-padded capacity

  char* ws = (char*)d_ws;
  size_t off = 0;
  auto take = [&](size_t bytes) -> char* {
    char* p = ws + off;
    off = (off + bytes + 255) & ~(size_t)255;
    return p;
  };
  int* row_ptr = (int*)take((size_t)(NT + 1) * 4);
  float* d_inv = (float*)take((size_t)NT * 4);
  int* rloc_g = (int*)take((size_t)NT * 4);
  int* cnt_chunk = (int*)take((size_t)NBUCK * NCH * 1024 * 4);
  int* gcur = (int*)take(NBUCK * 4);
  int* btot = (int*)take(NBUCK * 4);
  int* bbase = (int*)take(NBUCK * 4);
  uint2* edges = (uint2*)take(Ecap * 8);
  float* bufA = (float*)take((size_t)NT * 64 * 4);
  float* bufB = (float*)take((size_t)NT * 64 * 4);
  float* acc = (float*)take((size_t)NT * 64 * 4);
  float* ugen = (float*)take((size_t)BB * 64 * 4);
  float* igen = (float*)take((size_t)BB * 64 * 4);
  float* uio = (float*)take((size_t)BB * 64 * 4);
  float* iio = (float*)take((size_t)BB * 64 * 4);
  unsigned short* ugen_b = (unsigned short*)take((size_t)BB * 64 * 2);
  unsigned short* igen_b = (unsigned short*)take((size_t)BB * 64 * 2);
  unsigned short* uio_b = (unsigned short*)take((size_t)BB * 64 * 2);
  unsigned short* iio_b = (unsigned short*)take((size_t)BB * 64 * 2);
  float* negu = (float*)take((size_t)BB * 4);
  float* negi = (float*)take((size_t)BB * 4);
  double* accums = (double*)take(64);
  if (off > ws_size) return;
  // part[] (NBUCK*BCAP uint2 = 28.9MB) aliases bufB (38.4MB): last read in
  // k_fill2, bufB first written by k_agg#1.
  uint2* part = (uint2*)bufB;

  hipMemsetAsync(gcur, 0, NBUCK * 4, stream);
  hipMemsetAsync(edges, 0, Ecap * 8, stream);  // pad slots: idx 0, g = 0
  hipMemsetAsync(negu, 0, (size_t)BB * 4, stream);
  hipMemsetAsync(negi, 0, (size_t)BB * 4, stream);
  hipMemsetAsync(accums, 0, 64, stream);

  int gridP = (E + 4095) / 4096;
  k_part<<<gridP, 256, 0, stream>>>(h_list, t_list, gcur, part, E);
  k_count2<<<dim3(NBUCK, NCH), 256, 0, stream>>>(part, gcur, cnt_chunk);
  k_node<<<NBUCK, 256, 0, stream>>>(cnt_chunk, rloc_g, d_inv, btot);
  k_csr_base<<<1, 256, 0, stream>>>(btot, bbase, row_ptr);
  k_rowptr<<<(NT + 255) / 256, 256, 0, stream>>>(bbase, rloc_g, row_ptr);
  k_fill2<<<dim3(NBUCK, NCH), 256, 0, stream>>>(part, gcur, cnt_chunk, row_ptr,
                                                d_inv, edges);

  int nU4 = NU * 16, nTot4 = NT * 16;
  k_init<<<(nTot4 + 255) / 256, 256, 0, stream>>>((const float4*)user_emb, (const float4*)item_emb,
                                                  (float4*)bufA, (float4*)acc, nU4, nTot4);
  int gridAgg = NT / 4;
  k_agg<<<gridAgg, 256, 0, stream>>>(row_ptr, edges, bufA, bufB, acc);
  k_agg<<<gridAgg, 256, 0, stream>>>(row_ptr, edges, bufB, bufA, acc);
  k_agg<<<gridAgg, 256, 0, stream>>>(row_ptr, edges, bufA, bufB, acc);

  k_kl<<<512, 256, 0, stream>>>(acc, lin_w, lin_b, accums);
  k_batch_user<<<BB / 4, 256, 0, stream>>>(acc, user_emb, eps, user_int, lin_w, lin_b,
                                           users, pos_items, neg_items,
                                           ugen, uio, ugen_b, uio_b, accums);
  k_batch_item<<<BB / 4, 256, 0, stream>>>(acc, item_emb, eps, item_int, lin_w, lin_b,
                                           pos_items, neg_items,
                                           igen, iio, igen_b, iio_b, accums);
  k_int<<<1, 256, 0, stream>>>(user_int, item_int, accums);
  k_nce_mfma<<<dim3(64, 8), 256, 0, stream>>>(ugen_b, uio_b, igen_b, iio_b, negu, negi);
  k_nce_final<<<(2 * BB) / 4, 256, 0, stream>>>(ugen, uio, igen, iio, negu, negi, accums);
  k_fin<<<1, 64, 0, stream>>>(accums, out);
}